// Round 6
// baseline (611.467 us; speedup 1.0000x reference)
//
#include <hip/hip_runtime.h>
#include <math.h>
#include <stdint.h>

typedef unsigned short u16;
typedef unsigned int   u32;
typedef short short8 __attribute__((ext_vector_type(8)));
typedef float v4f    __attribute__((ext_vector_type(4)));

#define DEVI static __device__ __forceinline__

struct __align__(8)  U2 { u32 x, y; };
struct __align__(16) U4 { u32 x, y, z, w; };

static const int BB = 4, LL = 8192;
static const int BL = BB * LL;           // 32768 rows

DEVI float bf2f(u16 u){ u32 v = ((u32)u) << 16; float f; __builtin_memcpy(&f, &v, 4); return f; }
DEVI u16  f2bf(float f){ u32 u; __builtin_memcpy(&u, &f, 4); return (u16)((u + 0x7fffu + ((u >> 16) & 1u)) >> 16); }

// fast exact-gelu: erf via Abramowitz-Stegun 7.1.26 (max abs err 1.5e-7,
// far below bf16 rounding). ~15 VALU vs libm erff's ~100+.
DEVI float geluf(float x){
  float z = fabsf(x) * 0.7071067811865475f;
  float t = __builtin_amdgcn_rcpf(1.0f + 0.3275911f * z);
  float p = t * (0.254829592f + t * (-0.284496736f + t * (1.421413741f +
            t * (-1.453152027f + t * 1.061405429f))));
  float e = __builtin_amdgcn_exp2f(z * z * -1.4426950408889634f);
  float er = 1.0f - p * e;
  float s = (x < 0.0f) ? -er : er;
  return 0.5f * x * (1.0f + s);
}

DEVI void ldsload16(const void* g, void* l){
  __builtin_amdgcn_global_load_lds(
      (const __attribute__((address_space(1))) u32*)(uintptr_t)g,
      (__attribute__((address_space(3)))  u32*)(u32)(uintptr_t)l,
      16, 0, 0);
}

// ---------------- f32 -> bf16 convert, 4 tensors in one launch ----------------
__global__ __launch_bounds__(256) void k_cvt4(
    const float* __restrict__ s0, u16* __restrict__ d0, int n0,
    const float* __restrict__ s1, u16* __restrict__ d1, int n1,
    const float* __restrict__ s2, u16* __restrict__ d2, int n2,
    const float* __restrict__ s3, u16* __restrict__ d3, int n3){
  int i = blockIdx.x * 256 + threadIdx.x;
  if (i < n0){ d0[i] = f2bf(s0[i]); return; }
  i -= n0;
  if (i < n1){ d1[i] = f2bf(s1[i]); return; }
  i -= n1;
  if (i < n2){ d2[i] = f2bf(s2[i]); return; }
  i -= n2;
  if (i < n3){ d3[i] = f2bf(s3[i]); }
}

// ---------------- LayerNorm over 512 (f32 in, bf16 out) ----------------
__global__ __launch_bounds__(256) void k_ln1(const float* __restrict__ x, const float* __restrict__ g,
                                             const float* __restrict__ b, u16* __restrict__ xn){
  int row = blockIdx.x, t = threadIdx.x;
  const float2* xr = (const float2*)(x + (int64_t)row * 512);
  float2 p = xr[t];
  float s = p.x + p.y, ss = p.x * p.x + p.y * p.y;
  for (int off = 32; off; off >>= 1){ s += __shfl_down(s, off); ss += __shfl_down(ss, off); }
  __shared__ float red[8];
  int w = t >> 6, lane = t & 63;
  if (!lane){ red[w] = s; red[4 + w] = ss; }
  __syncthreads();
  s  = red[0] + red[1] + red[2] + red[3];
  ss = red[4] + red[5] + red[6] + red[7];
  float m = s * (1.0f / 512.0f), var = ss * (1.0f / 512.0f) - m * m;
  float rs = rsqrtf(var + 1e-5f);
  float2 gv = ((const float2*)g)[t], bv = ((const float2*)b)[t];
  float r0 = (p.x - m) * rs * gv.x + bv.x;
  float r1 = (p.y - m) * rs * gv.y + bv.y;
  ((u32*)(xn + (int64_t)row * 512))[t] = (u32)f2bf(r0) | ((u32)f2bf(r1) << 16);
}

// ---------------- LayerNorm over 128 (bf16 in, f32 params, bf16 out) ----------------
__global__ __launch_bounds__(256) void k_ln2(const u16* __restrict__ u, const float* __restrict__ g,
                                             const float* __restrict__ b, u16* __restrict__ un){
  int row = blockIdx.x * 4 + (threadIdx.x >> 6);
  int lane = threadIdx.x & 63;
  const u32* ur = (const u32*)(u + (int64_t)row * 128);
  u32 pv = ur[lane];
  float a = bf2f((u16)(pv & 0xffff)), c = bf2f((u16)(pv >> 16));
  float s = a + c, ss = a * a + c * c;
  for (int off = 32; off; off >>= 1){ s += __shfl_xor(s, off); ss += __shfl_xor(ss, off); }
  float m = s * (1.0f / 128.0f), var = ss * (1.0f / 128.0f) - m * m;
  float rs = rsqrtf(var + 1e-5f);
  float2 gv = ((const float2*)g)[lane], bv = ((const float2*)b)[lane];
  float r0 = (a - m) * rs * gv.x + bv.x;
  float r1 = (c - m) * rs * gv.y + bv.y;
  ((u32*)(un + (int64_t)row * 128))[lane] = (u32)f2bf(r0) | ((u32)f2bf(r1) << 16);
}

// ---------------- transpose un[BL,128] -> unT[(b,c,h), i] [8192,512] ----------------
__global__ __launch_bounds__(256) void k_transpose(const u16* __restrict__ un, u16* __restrict__ unT){
  int bc = blockIdx.x >> 3, it = blockIdx.x & 7;
  int b = bc >> 4, cc = bc & 15;
  __shared__ __align__(16) u16 tile[64][128];
  const u16* src = un + ((int64_t)(b * 8192 + cc * 512 + it * 64)) * 128;
  int t = threadIdx.x;
  for (int p = 0; p < 4; p++){
    int id = p * 256 + t; int ri = id >> 4, seg = id & 15;
    *(U4*)&tile[ri][seg * 8] = *(const U4*)(src + (int64_t)ri * 128 + seg * 8);
  }
  __syncthreads();
  u16* dst = unT + ((int64_t)(bc * 128)) * 512 + it * 64;
  for (int p = 0; p < 4; p++){
    int id = p * 256 + t; int h = id >> 3, seg = id & 7;
    U4 pk; u16* pv = (u16*)&pk;
    for (int k2 = 0; k2 < 8; k2++) pv[k2] = tile[seg * 8 + k2][h];
    *(U4*)(dst + (int64_t)h * 512 + seg * 8) = pk;
  }
}

// ---------------- DSS tables (f32 params) ----------------
__global__ __launch_bounds__(512) void k_prep(const float* lam_re, const float* lam_im,
    const float* C_re, const float* C_im,
    u16* ZC, u16* PC, u16* VC, u16* ccat, float* cre, float* cim, float* zT){
  int n = blockIdx.x, t = threadIdx.x;
  float lr = -expf(lam_re[n]);
  float li =  expf(lam_im[n]);
  float mag = expf(lr * (float)t), ph = li * (float)t;
  float er = mag * cosf(ph), ei = mag * sinf(ph);
  ZC[(int64_t)n * 512 + (511 - t)]         = f2bf(er);
  ZC[(int64_t)(512 + n) * 512 + (511 - t)] = f2bf(ei);
  VC[(int64_t)t * 1024 + n]       = f2bf(er);
  VC[(int64_t)t * 1024 + 512 + n] = f2bf(-ei);
  float mag2 = expf(lr * (float)(t + 1)), ph2 = li * (float)(t + 1);
  PC[(int64_t)t * 1024 + n]       = f2bf(mag2 * cosf(ph2));
  PC[(int64_t)t * 1024 + 512 + n] = f2bf(-mag2 * sinf(ph2));
  if (t == 0){
    float m5 = expf(lr * 512.0f), p5 = li * 512.0f;
    zT[n] = m5 * cosf(p5); zT[512 + n] = m5 * sinf(p5);
  }
  if (t < 128){
    float e1m = expf(lr);
    float e1r = e1m * cosf(li), e1i = e1m * sinf(li);
    float nr = e1r - 1.0f, ni = e1i;
    float d2 = lr * lr + li * li;
    float qr = (nr * lr + ni * li) / d2, qi = (ni * lr - nr * li) / d2;
    float Cr = C_re[t * 512 + n], Ci = C_im[t * 512 + n];
    float vr = Cr * qr - Ci * qi, vi = Cr * qi + Ci * qr;
    cre[t * 512 + n] = vr; cim[t * 512 + n] = vi;
    ccat[(int64_t)t * 1024 + n] = f2bf(vr); ccat[(int64_t)t * 1024 + 512 + n] = f2bf(vi);
  }
}

// ---------------- kern[d,h] = sum_n VC[d,n]*ccat[h,n] (512x128, K=1024) ----------------
__global__ __launch_bounds__(128) void k_kern(const u16* __restrict__ VC,
                                              const u16* __restrict__ ccat,
                                              float* __restrict__ kern){
  __shared__ __align__(16) u16 vrow[1024];
  int d = blockIdx.x, h = threadIdx.x;
  *(U4*)&vrow[h * 8] = *(const U4*)(VC + (int64_t)d * 1024 + h * 8);
  __syncthreads();
  const u16* cr = ccat + (int64_t)h * 1024;
  float s = 0.0f;
  #pragma unroll 4
  for (int k = 0; k < 1024; k += 8){
    short8 a = *(const short8*)&vrow[k];
    short8 b = *(const short8*)(cr + k);
    #pragma unroll
    for (int j = 0; j < 8; j++) s += bf2f((u16)a[j]) * bf2f((u16)b[j]);
  }
  kern[(int64_t)d * 128 + h] = s;
}

// ---------------- block-Toeplitz build ----------------
__global__ __launch_bounds__(512) void k_rcat(const float* __restrict__ kern, u16* __restrict__ Rcat){
  int h = blockIdx.x >> 7, a = blockIdx.x & 127;
  int kcol = threadIdx.x;
  int d = 3 - (kcol >> 7);
  int delay = d * 128 + a - (kcol & 127);
  float val = (delay >= 0 && delay < 512) ? kern[delay * 128 + h] : 0.0f;
  Rcat[((int64_t)(h * 128 + a)) * 512 + kcol] = f2bf(val);
}

// ---------------- chunk scan + W = c * Scarry ----------------
__global__ __launch_bounds__(256) void k_scan(const float* __restrict__ S, const float* __restrict__ cre,
    const float* __restrict__ cim, const float* __restrict__ zT, u16* __restrict__ WT){
  int tid = blockIdx.x * 256 + threadIdx.x;   // 262144
  int n = tid & 511, bh = tid >> 9, b = bh >> 7, h = bh & 127;
  float cr = cre[h * 512 + n], ci = cim[h * 512 + n];
  float zr = zT[n], zi = zT[512 + n];
  float sR = 0.0f, sI = 0.0f;
  for (int cc = 0; cc < 16; cc++){
    int64_t m = (int64_t)(b * 16 + cc) * 128 + h;
    float wR = cr * sR - ci * sI, wI = cr * sI + ci * sR;
    WT[m * 1024 + n] = f2bf(wR);
    WT[m * 1024 + 512 + n] = f2bf(wI);
    float aR = S[m * 1024 + n], aI = S[m * 1024 + 512 + n];
    float nR = zr * sR - zi * sI + aR;
    sI = zr * sI + zi * sR + aI;
    sR = nR;
  }
}

// ---------------- y = Yloc + Ycross + un*D_skip (tiled, coalesced both sides) ----------------
// Yloc layout [h][ii][bc]: bc (64) is the only contiguous axis -> read along bc,
// LDS-transpose tile [128h][64bc], write y along h (contiguous 256B). Old
// version read Yloc at stride 128KB (4B useful per 64B line, ~16x overfetch).
__global__ __launch_bounds__(512) void k_assemble2(const float* __restrict__ Yloc,
    const float* __restrict__ Ycross, const u16* __restrict__ un,
    const float* __restrict__ Dskip, u16* __restrict__ y){
  __shared__ float tile[128][65];
  int ii = blockIdx.x;           // 0..511
  int t = threadIdx.x;
  int hl = t >> 6;               // 0..7
  int bcl = t & 63;
  #pragma unroll
  for (int p = 0; p < 16; p++){
    int h = p * 8 + hl;
    tile[h][bcl] = Yloc[((int64_t)(h * 512 + ii)) * 64 + bcl];
  }
  __syncthreads();
  int h = t & 127;
  int bcr = t >> 7;              // 0..3
  float dk = Dskip[h];
  #pragma unroll
  for (int p = 0; p < 16; p++){
    int bc = p * 4 + bcr;
    int b = bc >> 4, cc = bc & 15;
    int64_t e = ((int64_t)b * 8192 + cc * 512 + ii) * 128 + h;
    float val = tile[h][bc]
              + Ycross[(int64_t)ii * 8192 + (int64_t)bc * 128 + h]
              + bf2f(un[e]) * dk;
    y[e] = f2bf(val);
  }
}

// ---------------- generic BT GEMM: C[m,n] = sum_k A[m,k]*B[n,k] ----------------
// EPI: 0 = f32 direct store; 1 = gelu->bf16
// TRI: block-Toeplitz mode (A has 128 rows; per row-block ib=by: A base shift
//      (3-ib)*128, K_eff=(ib+1)*128). Yloc local-conv in ONE launch.
template<int EPI, bool TRI = false>
__global__ __launch_bounds__(256) void k_gemm(
    const u16* __restrict__ A, int64_t lda, int64_t aZ,
    const u16* __restrict__ B, int64_t ldb, int64_t bZ,
    void* Cp, int64_t ldc, int64_t cZ,
    int K, int Nvalid,
    const u16* aux1, const float* auxf1, const float* auxf2)
{
  __shared__ union __align__(16) SMU { u16 st[2][4096]; float ep[4][1088]; } sm;
  const int tid = threadIdx.x;
  const int lane = tid & 63, w = tid >> 6;
  const int wr = w >> 1, wc = w & 1, q = lane >> 4, c16 = lane & 15;
  const int sRow = lane >> 2, sSeg = lane & 3;
  const int z = blockIdx.z;

  int bx = blockIdx.x, by = blockIdx.y;
  if (!TRI && (gridDim.y & 7) == 0 && gridDim.x > 1){
    u32 idx = by * gridDim.x + bx;
    u32 xcd = idx & 7, s = idx >> 3;
    bx = s % gridDim.x;
    by = (s / gridDim.x) * 8 + xcd;
  }
  const int64_t m0 = (int64_t)by * 128;
  const int64_t n0 = (int64_t)bx * 128;

  const u16* Ab = A + (int64_t)z * aZ;
  const u16* Bp = B + (int64_t)z * bZ;
  int Keff = K;
  if (TRI){
    Ab += 384 - m0;              // (3-ib)*128 column shift
    Keff = (int)(m0 + 128);      // (ib+1)*128
  }

  v4f acc[4][4];
  #pragma unroll
  for (int i = 0; i < 4; i++)
    #pragma unroll
    for (int j = 0; j < 4; j++)
      acc[i][j] = (v4f)0.0f;

  for (int k0 = 0; k0 < Keff; k0 += 32){
    #pragma unroll
    for (int half = 0; half < 2; half++){
      int r0 = (half * 4 + w) * 16;
      int64_t arow = (TRI ? (int64_t)0 : m0) + r0 + sRow;
      ldsload16(Ab + arow * lda + k0 + sSeg * 8, &sm.st[0][r0 * 32]);
      int64_t brow = n0 + r0 + sRow;
      if (brow >= Nvalid) brow = Nvalid - 1;
      ldsload16(Bp + brow * ldb + k0 + sSeg * 8, &sm.st[1][r0 * 32]);
    }
    __syncthreads();
    short8 af[4], bfr[4];
    const u16* aB = &sm.st[0][(wr * 64 + c16) * 32 + q * 8];
    const u16* bB = &sm.st[1][(wc * 64 + c16) * 32 + q * 8];
    #pragma unroll
    for (int i = 0; i < 4; i++) af[i]  = *(const short8*)(aB + i * 512);
    #pragma unroll
    for (int j = 0; j < 4; j++) bfr[j] = *(const short8*)(bB + j * 512);
    #pragma unroll
    for (int i = 0; i < 4; i++)
      #pragma unroll
      for (int j = 0; j < 4; j++)
        acc[i][j] = __builtin_amdgcn_mfma_f32_16x16x32_bf16(af[i], bfr[j], acc[i][j], 0, 0, 0);
    __syncthreads();
  }

  if (EPI == 0){
    float* Cf = (float*)Cp + (int64_t)z * cZ;
    #pragma unroll
    for (int i = 0; i < 4; i++)
      #pragma unroll
      for (int j = 0; j < 4; j++){
        int64_t gr = m0 + wr * 64 + i * 16 + q * 4;
        int64_t gc = n0 + wc * 64 + j * 16 + c16;
        if (gc < Nvalid){
          #pragma unroll
          for (int r = 0; r < 4; r++)
            Cf[(gr + r) * ldc + gc] = acc[i][j][r];
        }
      }
    return;
  }

  // bf16 output path: per-wave LDS transpose for packed stores
  u16* Cb = (u16*)Cp + (int64_t)z * cZ;
  float* ep = sm.ep[w];
  for (int i = 0; i < 4; i++){
    #pragma unroll
    for (int j = 0; j < 4; j++)
      #pragma unroll
      for (int r = 0; r < 4; r++){
        float vv = acc[i][j][r];
        if (EPI == 1) vv = geluf(vv);
        ep[(q * 4 + r) * 68 + j * 16 + c16] = vv;
      }
    #pragma unroll
    for (int p = 0; p < 4; p++){
      int id = p * 64 + lane;
      int row = id >> 4, cg = id & 15;
      float o0 = ep[row * 68 + cg * 4 + 0];
      float o1 = ep[row * 68 + cg * 4 + 1];
      float o2 = ep[row * 68 + cg * 4 + 2];
      float o3 = ep[row * 68 + cg * 4 + 3];
      int64_t gr = m0 + wr * 64 + i * 16 + row;
      int64_t gc = n0 + wc * 64 + cg * 4;
      if (gc < Nvalid){
        U2 outp;
        outp.x = (u32)f2bf(o0) | ((u32)f2bf(o1) << 16);
        outp.y = (u32)f2bf(o2) | ((u32)f2bf(o3) << 16);
        *(U2*)(Cb + gr * ldc + gc) = outp;
      }
    }
  }
}

// ======= 256x256 GEMM, double-buffered, ONE barrier per K-tile =======
// (structure validated r4; equals the 8-phase variant in perf, simpler)
#define FENCE __builtin_amdgcn_sched_barrier(0)
#define BARX  __builtin_amdgcn_s_barrier()

#define STAGE(SRC, LD, TBASE, SEL, KT)                                          \
  { const u16* _g = (SRC) + (int64_t)(KT) * 64 + (int64_t)((SEL) * 128 + wid * 8) * (LD); \
    u16* _lb = (TBASE) + ((SEL) * 128 + wid * 8) * 64;                          \
    ldsload16(_g, _lb);                                                         \
    ldsload16(_g + (int64_t)64 * (LD), _lb + 64 * 64);                          \
  }

#define MFMAQ(QM, QN, BQ)                                                       \
  __builtin_amdgcn_s_setprio(1);                                                \
  _Pragma("unroll")                                                             \
  for (int mi = 0; mi < 4; mi++)                                                \
    _Pragma("unroll")                                                           \
    for (int ni = 0; ni < 2; ni++){                                             \
      acc[(QM)*4+mi][(QN)*2+ni] = __builtin_amdgcn_mfma_f32_16x16x32_bf16(      \
          af[mi][0], BQ[ni][0], acc[(QM)*4+mi][(QN)*2+ni], 0, 0, 0);            \
      acc[(QM)*4+mi][(QN)*2+ni] = __builtin_amdgcn_mfma_f32_16x16x32_bf16(      \
          af[mi][1], BQ[ni][1], acc[(QM)*4+mi][(QN)*2+ni], 0, 0, 0);            \
    }                                                                           \
  __builtin_amdgcn_s_setprio(0);

#define DS_READ_A(OFF)                                                          \
    _Pragma("unroll")                                                           \
    for (int mi = 0; mi < 4; mi++){                                             \
      af[mi][0] = *(const short8*)(Ac + (OFF) + abase + mi * 2048 + kx0);       \
      af[mi][1] = *(const short8*)(Ac + (OFF) + abase + mi * 2048 + kx1);       \
    }
#define DS_READ_B(BQ, OFF)                                                      \
    _Pragma("unroll")                                                           \
    for (int ni = 0; ni < 2; ni++){                                             \
      BQ[ni][0] = *(const short8*)(Bc + (OFF) + bbase + ni * 2048 + kx0);       \
      BQ[ni][1] = *(const short8*)(Bc + (OFF) + bbase + ni * 2048 + kx1);       \
    }

#define DO_TILE(T, CURB, NXTB)                                                  \
  {                                                                             \
    const char* Ac = (const char*)(CURB);                                       \
    const char* Bc = Ac + 32768;                                                \
    if ((T) + 1 < NT){                                                          \
      u16* Ab_ = (NXTB); u16* Bb_ = (NXTB) + 16384;                             \
      STAGE(Asrc, lda, Ab_, 0, (T) + 1);                                        \
      STAGE(Asrc, lda, Ab_, 1, (T) + 1);                                        \
      STAGE(Bsrc, ldb, Bb_, 0, (T) + 1);                                        \
      STAGE(Bsrc, ldb, Bb_, 1, (T) + 1);                                        \
    }                                                                           \
    DS_READ_A(0) DS_READ_B(bq0, 0) DS_READ_B(bq1, 16384)                        \
    MFMAQ(0, 0, bq0);                                                           \
    MFMAQ(0, 1, bq1);                                                           \
    DS_READ_A(16384)                                                            \
    MFMAQ(1, 1, bq1);                                                           \
    MFMAQ(1, 0, bq0);                                                           \
    asm volatile("s_waitcnt lgkmcnt(0)" ::: "memory");                          \
    if ((T) + 1 < NT) asm volatile("s_waitcnt vmcnt(0)" ::: "memory");          \
    FENCE; BARX; FENCE;                                                         \
  }

template<int EPI>
__global__ __launch_bounds__(512) void k_gemm256(
    const u16* __restrict__ A, int64_t lda,
    const u16* __restrict__ B, int64_t ldb,
    void* __restrict__ Cp, int64_t ldc, int K,
    const u16* __restrict__ aux1,
    const float* __restrict__ auxf1, const float* __restrict__ auxf2)
{
  extern __shared__ __align__(16) u16 smd[];   // 2 x 64KB: {A0,A1 | B0,B1}
  const int tid = threadIdx.x, wid = tid >> 6, lane = tid & 63;
  const int wr = wid >> 2, wc = wid & 3, c16 = lane & 15;
  const int q4 = (lane >> 4) << 2;

  int bx = blockIdx.x, by = blockIdx.y;        // bijective XCD swizzle
  if ((gridDim.y & 7) == 0 && gridDim.x > 1){
    u32 idx = by * gridDim.x + bx;
    u32 xcd = idx & 7, s = idx >> 3;
    bx = s % gridDim.x;
    by = (s / gridDim.x) * 8 + xcd;
  }
  const int64_t m0 = (int64_t)by * 256;
  const int64_t n0 = (int64_t)bx * 256;
  const int NT = K >> 6;

  const int rowin = lane >> 3;
  const int colel = 8 * ((lane & 7) ^ rowin);
  const u16* Asrc = A + (m0 + rowin) * lda + colel;
  const u16* Bsrc = B + (n0 + rowin) * ldb + colel;

  const int kx0 = ((lane >> 4) << 4) ^ ((lane & 7) << 4);
  const int kx1 = kx0 ^ 64;
  const int abase = (wr * 64 + c16) * 128;
  const int bbase = (wc * 32 + c16) * 128;

  u16* buf0 = smd;
  u16* buf1 = smd + 32768;

  v4f acc[8][4];
  #pragma unroll
  for (int i = 0; i < 8; i++)
    #pragma unroll
    for (int j = 0; j < 4; j++) acc[i][j] = (v4f)0.0f;

  short8 af[4][2], bq0[2][2], bq1[2][2];

  STAGE(Asrc, lda, buf0,         0, 0);
  STAGE(Asrc, lda, buf0,         1, 0);
  STAGE(Bsrc, ldb, buf0 + 16384, 0, 0);
  STAGE(Bsrc, ldb, buf0 + 16384, 1, 0);
  asm volatile("s_waitcnt vmcnt(0)" ::: "memory");
  FENCE; BARX; FENCE;

  for (int t = 0; t < NT; t += 2){   // NT even
    DO_TILE(t,     buf0, buf1)
    DO_TILE(t + 1, buf1, buf0)
  }

  if (EPI == 0){
    float* C = (float*)Cp;
    #pragma unroll
    for (int qm = 0; qm < 2; qm++)
      #pragma unroll
      for (int mi = 0; mi < 4; mi++){
        int64_t gr = m0 + qm * 128 + wr * 64 + mi * 16 + q4;
        #pragma unroll
        for (int qn = 0; qn < 2; qn++)
          #pragma unroll
          for (int ni = 0; ni < 2; ni++){
            int64_t gc = n0 + qn * 128 + wc * 32 + ni * 16 + c16;
            v4f a = acc[qm * 4 + mi][qn * 2 + ni];
            float bo = auxf2[gc];
            #pragma unroll
            for (int r = 0; r < 4; r++)
              C[(gr + r) * ldc + gc] = a[r] + auxf1[(gr + r) * ldc + gc] + bo;
          }
      }
    return;
  }

  // bf16 epilogue: per-wave LDS transpose, packed 16B stores.
  u16* Cb = (u16*)Cp;
  float* scr = (float*)smd + wid * 528;
  const int erow = lane >> 2, eseg = lane & 3;
  #pragma unroll
  for (int qm = 0; qm < 2; qm++)
    #pragma unroll
    for (int mi = 0; mi < 4; mi++)
      #pragma unroll
      for (int qn = 0; qn < 2; qn++){
        #pragma unroll
        for (int ni = 0; ni < 2; ni++){
          v4f a = acc[qm * 4 + mi][qn * 2 + ni];
          #pragma unroll
          for (int r = 0; r < 4; r++){
            float vv = a[r];
            if (EPI == 1) vv = geluf(vv);
            scr[(q4 + r) * 33 + ni * 16 + c16] = vv;
          }
        }
        float o[8];
        #pragma unroll
        for (int kq = 0; kq < 8; kq++) o[kq] = scr[erow * 33 + eseg * 8 + kq];
        int64_t gr = m0 + qm * 128 + wr * 64 + mi * 16 + erow;
        int64_t gc = n0 + qn * 128 + wc * 32 + eseg * 8;
        U4 outp; u16* op = (u16*)&outp;
        #pragma unroll
        for (int kq = 0; kq < 8; kq++) op[kq] = f2bf(o[kq]);
        *(U4*)(Cb + gr * ldc + gc) = outp;
      }
}

// ======= K=128-specialized GEMM for uc = y@Wuc^T fused *v (in place) =======
// A-strip (y, 256x128 = 64KB) pinned in LDS for the whole block; loop nj over
// 4 N-tiles of 256 (grid (2,128) -> 1 block/CU, 1 round). Per nj: MFMA from
// resident A+B, barrier, stage B(nj+1) EARLY (T14: latency hides under the
// epilogue), epilogue with pipelined v-prefetch (ping-pong U4 regs, static
// indices), vmcnt(0)+barrier. Saves 3 of 4 prologue/epilogue rounds vs
// k_gemm256 and removes the latency-exposed per-group v loads.
__global__ __launch_bounds__(512) void k_gemmK128(
    const u16* __restrict__ A,      // y [32768,128]
    const u16* __restrict__ B,      // Wuc_b [2048,128]
    u16* __restrict__ C)            // v in-place [32768,2048]; also aux (mul)
{
  extern __shared__ __align__(16) u16 smd[];   // A 64KB | B 64KB | scr 16.9KB
  const int tid = threadIdx.x, wid = tid >> 6, lane = tid & 63;
  const int wr = wid >> 2, wc = wid & 3, c16 = lane & 15;
  const int q4 = (lane >> 4) << 2;

  int bx = blockIdx.x, by = blockIdx.y;        // bijective XCD swizzle (nwg=256)
  {
    u32 idx = by * gridDim.x + bx;
    u32 xcd = idx & 7, s = idx >> 3;
    bx = s % gridDim.x;
    by = (s / gridDim.x) * 8 + xcd;
  }
  const int64_t m0 = (int64_t)by * 256;
  const int64_t nbase = (int64_t)bx * 1024;

  const int rowin = lane >> 3;
  const int colel = 8 * ((lane & 7) ^ rowin);
  const u16* Asrc = A + (m0 + rowin) * 128 + colel;

  const int kx0 = ((lane >> 4) << 4) ^ ((lane & 7) << 4);
  const int kx1 = kx0 ^ 64;
  const int abase = (wr * 64 + c16) * 128;
  const int bbase = (wc * 32 + c16) * 128;

  u16* Abuf = smd;                 // 2 k-tiles x 32KB
  u16* Bbuf = smd + 32768;         // 2 k-tiles x 32KB
  float* scr = (float*)(smd + 65536) + wid * 528;

  const int erow = lane >> 2, eseg = lane & 3;
  short8 af[4][2], bq0[2][2], bq1[2][2];

  // prologue: A (both k-tiles) + B(nj=0)
  {
    const u16* Bs0 = B + (nbase + rowin) * 128 + colel;
    STAGE(Asrc, 128, Abuf,         0, 0);
    STAGE(Asrc, 128, Abuf,         1, 0);
    STAGE(Asrc, 128, Abuf + 16384, 0, 1);
    STAGE(Asrc, 128, Abuf + 16384, 1, 1);
    STAGE(Bs0,  128, Bbuf,         0, 0);
    STAGE(Bs0,  128, Bbuf,         1, 0);
    STAGE(Bs0,  128, Bbuf + 16384, 0, 1);
    STAGE(Bs0,  128, Bbuf + 16384, 1, 1);
  }
  asm volatile("s_waitcnt vmcnt(0)" ::: "memory");
  FENCE; BARX; FENCE;

  #pragma unroll
  for (int nj = 0; nj < 4; nj++){
    const int64_t n0 = nbase + nj * 256;

    v4f acc[8][4];
    #pragma unroll
    for (int i = 0; i < 8; i++)
      #pragma unroll
      for (int j = 0; j < 4; j++) acc[i][j] = (v4f)0.0f;

    #pragma unroll
    for (int kt = 0; kt < 2; kt++){
      const char* Ac = (const char*)Abuf + kt * 32768;
      const char* Bc = (const char*)Bbuf + kt * 32768;
      DS_READ_A(0) DS_READ_B(bq0, 0) DS_READ_B(bq1, 16384)
      MFMAQ(0, 0, bq0);
      MFMAQ(0, 1, bq1);
      DS_READ_A(16384)
      MFMAQ(1, 1, bq1);
      MFMAQ(1, 0, bq0);
    }
    asm volatile("s_waitcnt lgkmcnt(0)" ::: "memory");
    FENCE; BARX; FENCE;          // all waves done reading Bbuf

    if (nj < 3){                 // stage B(nj+1) early; hides under epilogue
      const u16* Bs = B + (nbase + (nj + 1) * 256 + rowin) * 128 + colel;
      STAGE(Bs, 128, Bbuf,         0, 0);
      STAGE(Bs, 128, Bbuf,         1, 0);
      STAGE(Bs, 128, Bbuf + 16384, 0, 1);
      STAGE(Bs, 128, Bbuf + 16384, 1, 1);
    }

    // epilogue: t = acc * v, bf16 out (in place over v). 8 groups (qm,mi),
    // v-prefetch pipelined one group ahead (static reg indices).
    U4 pvA[2], pvB[2];
    {
      int64_t gr = m0 + wr * 64 + erow;               // qm=0, mi=0 row base
      pvA[0] = *(const U4*)(C + gr * 2048 + n0 + wc * 32 + eseg * 8);
      pvA[1] = *(const U4*)(C + gr * 2048 + n0 + 128 + wc * 32 + eseg * 8);
    }
    #pragma unroll
    for (int g = 0; g < 8; g++){
      const int qm = g >> 2, mi = g & 3;
      int64_t gr0 = m0 + qm * 128 + wr * 64 + mi * 16;
      if (g < 7){
        const int qn2 = (g + 1) >> 2, mn2 = (g + 1) & 3;
        int64_t gr2 = m0 + qn2 * 128 + wr * 64 + mn2 * 16 + erow;
        if (g & 1){
          pvA[0] = *(const U4*)(C + gr2 * 2048 + n0 + wc * 32 + eseg * 8);
          pvA[1] = *(const U4*)(C + gr2 * 2048 + n0 + 128 + wc * 32 + eseg * 8);
        } else {
          pvB[0] = *(const U4*)(C + gr2 * 2048 + n0 + wc * 32 + eseg * 8);
          pvB[1] = *(const U4*)(C + gr2 * 2048 + n0 + 128 + wc * 32 + eseg * 8);
        }
      }
      #pragma unroll
      for (int qn = 0; qn < 2; qn++){
        #pragma unroll
        for (int ni = 0; ni < 2; ni++){
          v4f a = acc[qm * 4 + mi][qn * 2 + ni];
          #pragma unroll
          for (int r = 0; r < 4; r++)
            scr[(q4 + r) * 33 + ni * 16 + c16] = a[r];
        }
        float o[8];
        #pragma unroll
        for (int kq = 0; kq < 8; kq++) o[kq] = scr[erow * 33 + eseg * 8 + kq];
        U4 pv = (g & 1) ? pvB[qn] : pvA[qn];
        const u16* pp = (const u16*)&pv;
        U4 outp; u16* op = (u16*)&outp;
        #pragma unroll
        for (int kq = 0; kq < 8; kq++) op[kq] = f2bf(o[kq] * bf2f(pp[kq]));
        int64_t gr = gr0 + erow;
        int64_t gc = n0 + qn * 128 + wc * 32 + eseg * 8;
        *(U4*)(C + gr * 2048 + gc) = outp;
      }
    }

    if (nj < 3){
      asm volatile("s_waitcnt vmcnt(0)" ::: "memory");
      FENCE; BARX; FENCE;
    }
  }
}

extern "C" void kernel_launch(void* const* d_in, const int* in_sizes, int n_in,
                              void* d_out, int out_size, void* d_ws, size_t ws_size,
                              hipStream_t stream) {
  (void)in_sizes; (void)n_in; (void)out_size; (void)ws_size;
  const float* x      = (const float*)d_in[0];
  const float* norm_g = (const float*)d_in[1];
  const float* norm_b = (const float*)d_in[2];
  const float* W_v    = (const float*)d_in[3];
  const float* W_u    = (const float*)d_in[4];
  const float* W_uc   = (const float*)d_in[5];
  const float* W_o    = (const float*)d_in[6];
  const float* b_o    = (const float*)d_in[7];
  const float* dss_g  = (const float*)d_in[8];
  const float* dss_b  = (const float*)d_in[9];
  const float* lam_re = (const float*)d_in[10];
  const float* lam_im = (const float*)d_in[11];
  const float* C_re   = (const float*)d_in[12];
  const float* C_im   = (const float*)d_in[13];
  const float* D_skip = (const float*)d_in[14];

  // ---- d_out (67.1 MB f32) doubles as scratch for xn + 2 bf16 weights (dead before final GEMM) ----
  char* ob = (char*)d_out;
  u16* xn    = (u16*)(ob);                         // 33,554,432 B
  u16* Wv_b  = (u16*)(ob + 33554432ull);           //  2,097,152 B
  u16* Wu_b  = (u16*)(ob + 35651584ull);           //    131,072 B

  // ---- workspace layout (aliased by lifetime), total ~224 MiB ----
  char* ws = (char*)d_ws;
  const size_t R1      = 134217728ull;             // after v: u -> (Rcat | WT)
  const size_t OFF_UN  = R1 + 33554432ull;
  const size_t OFF_UNT = OFF_UN + 8388608ull;      // unT, later y
  const size_t OFF_R2  = OFF_UNT + 8388608ull;     // S -> (Ycross | Yloc)
  const size_t OFF_TAB = OFF_R2 + 33554432ull;

  u16*  v     = (u16*)(ws + 0);                    // [32768,2048] bf16
  u16*  u     = (u16*)(ws + R1);
  u16*  Rcat  = (u16*)(ws + R1);                   // 16.8 MB
  u16*  WT    = (u16*)(ws + R1 + 16777216ull);     // 16.8 MB
  u16*  un    = (u16*)(ws + OFF_UN);
  u16*  unT   = (u16*)(ws + OFF_UNT);
  u16*  y     = (u16*)(ws + OFF_UNT);
  float* S    = (float*)(ws + OFF_R2);
  float* Ycross = (float*)(ws + OFF_R2);
  float* Yloc = (float*)(ws + OFF_R2 + 16777216ull);
  char* tp = ws + OFF_TAB;
  u16*  ZC   = (u16*)tp;            tp += 1048576;
  u16*  PC   = (u16*)tp;            tp += 1048576;
  u16*  VC   = (u16*)tp;            tp += 1048576;
  u16*  ccat = (u16*)tp;            tp += 262144;
  float* cre = (float*)tp;          tp += 262144;
  float* cim = (float*)tp;          tp += 262144;
  float* zT  = (float*)tp;          tp += 4096;
  float* kern= (float*)tp;          tp += 262144;
  u16*  Wo_b = (u16*)tp;            tp += 2097152;
  u16*  Wuc_b= (u16*)tp;            tp += 524288;

  // weight conversions (f32 -> bf16), one launch
  k_cvt4<<<9472, 256, 0, stream>>>(W_v, Wv_b, 2048 * 512,
                                   W_u, Wu_b, 128 * 512,
                                   W_uc, Wuc_b, 2048 * 128,
                                   W_o, Wo_b, 512 * 2048);

  k_ln1<<<BL, 256, 0, stream>>>(x, norm_g, norm_b, xn);
  k_prep<<<512, 512, 0, stream>>>(lam_re, lam_im, C_re, C_im, ZC, PC, VC, ccat, cre, cim, zT);
  // kern while VC/ccat are L2-hot
  k_kern<<<512, 128, 0, stream>>>(VC, ccat, kern);

  // v = gelu(xn @ W_v^T)   [32768,2048] bf16
  k_gemm256<1><<<dim3(8, 128), 512, 131072, stream>>>(xn, 512, Wv_b, 512, v, 2048, 512, nullptr, nullptr, nullptr);
  // u = gelu(xn @ W_u^T)   [32768,128] bf16 (N=128 -> old template)
  k_gemm<1><<<dim3(1, 256, 1), 256, 0, stream>>>(xn, 512, 0, Wu_b, 512, 0, u, 128, 0, 512, 128, nullptr, nullptr, nullptr);
  k_ln2<<<BL / 4, 256, 0, stream>>>(u, dss_g, dss_b, un);
  k_transpose<<<512, 256, 0, stream>>>(un, unT);

  k_rcat<<<16384, 512, 0, stream>>>(kern, Rcat);

  // chunk states: S[m,n'] = sum_i unT[m,i]*ZC[n',i]  [8192,1024] f32
  k_gemm<0><<<dim3(8, 64, 1), 256, 0, stream>>>(unT, 512, 0, ZC, 512, 0, S, 1024, 0, 512, 1024, nullptr, nullptr, nullptr);
  k_scan<<<1024, 256, 0, stream>>>(S, cre, cim, zT, WT);
  // injection: Ycross[i,m] = sum_n' PC[i,n']*WT[m,n']  [512,8192] f32
  k_gemm<0><<<dim3(64, 4, 1), 256, 0, stream>>>(PC, 1024, 0, WT, 1024, 0, Ycross, 8192, 0, 1024, 8192, nullptr, nullptr, nullptr);
  // local conv via block-Toeplitz, single launch (TRI mode: by = i_blk)
  k_gemm<0, true><<<dim3(1, 4, 128), 256, 0, stream>>>(
      Rcat, 512, 65536, unT, 65536, 512, Yloc, 64, 32768, 512, 64, nullptr, nullptr, nullptr);
  // y assembled with coalesced Yloc reads (LDS transpose per ii)
  k_assemble2<<<512, 512, 0, stream>>>(Yloc, Ycross, un, D_skip, y);

  // uc = y @ W_uc^T, fused t = uc*v (in place over v) -- K=128 specialized
  k_gemmK128<<<dim3(2, 128), 512, 148480, stream>>>(y, Wuc_b, v);
  // out = t @ W_o^T + b_o + x   (f32 out)
  k_gemm256<0><<<dim3(2, 128), 512, 131072, stream>>>(v, 2048, Wo_b, 2048, d_out, 512, 2048, nullptr, x, b_o);
}

// Round 7
// 604.351 us; speedup vs baseline: 1.0118x; 1.0118x over previous
//
#include <hip/hip_runtime.h>
#include <math.h>
#include <stdint.h>

typedef unsigned short u16;
typedef unsigned int   u32;
typedef short short8 __attribute__((ext_vector_type(8)));
typedef float v4f    __attribute__((ext_vector_type(4)));

#define DEVI static __device__ __forceinline__

struct __align__(8)  U2 { u32 x, y; };
struct __align__(16) U4 { u32 x, y, z, w; };

static const int BB = 4, LL = 8192;
static const int BL = BB * LL;           // 32768 rows

DEVI float bf2f(u16 u){ u32 v = ((u32)u) << 16; float f; __builtin_memcpy(&f, &v, 4); return f; }
DEVI u16  f2bf(float f){ u32 u; __builtin_memcpy(&u, &f, 4); return (u16)((u + 0x7fffu + ((u >> 16) & 1u)) >> 16); }

// fast exact-gelu: erf via Abramowitz-Stegun 7.1.26 (max abs err 1.5e-7,
// far below bf16 rounding). ~15 VALU vs libm erff's ~100+.
DEVI float geluf(float x){
  float z = fabsf(x) * 0.7071067811865475f;
  float t = __builtin_amdgcn_rcpf(1.0f + 0.3275911f * z);
  float p = t * (0.254829592f + t * (-0.284496736f + t * (1.421413741f +
            t * (-1.453152027f + t * 1.061405429f))));
  float e = __builtin_amdgcn_exp2f(z * z * -1.4426950408889634f);
  float er = 1.0f - p * e;
  float s = (x < 0.0f) ? -er : er;
  return 0.5f * x * (1.0f + s);
}

DEVI void ldsload16(const void* g, void* l){
  __builtin_amdgcn_global_load_lds(
      (const __attribute__((address_space(1))) u32*)(uintptr_t)g,
      (__attribute__((address_space(3)))  u32*)(u32)(uintptr_t)l,
      16, 0, 0);
}

// ---------------- f32 -> bf16 convert, 4 tensors in one launch ----------------
__global__ __launch_bounds__(256) void k_cvt4(
    const float* __restrict__ s0, u16* __restrict__ d0, int n0,
    const float* __restrict__ s1, u16* __restrict__ d1, int n1,
    const float* __restrict__ s2, u16* __restrict__ d2, int n2,
    const float* __restrict__ s3, u16* __restrict__ d3, int n3){
  int i = blockIdx.x * 256 + threadIdx.x;
  if (i < n0){ d0[i] = f2bf(s0[i]); return; }
  i -= n0;
  if (i < n1){ d1[i] = f2bf(s1[i]); return; }
  i -= n1;
  if (i < n2){ d2[i] = f2bf(s2[i]); return; }
  i -= n2;
  if (i < n3){ d3[i] = f2bf(s3[i]); }
}

// ---------------- LayerNorm over 512 (f32 in, bf16 out) ----------------
__global__ __launch_bounds__(256) void k_ln1(const float* __restrict__ x, const float* __restrict__ g,
                                             const float* __restrict__ b, u16* __restrict__ xn){
  int row = blockIdx.x, t = threadIdx.x;
  const float2* xr = (const float2*)(x + (int64_t)row * 512);
  float2 p = xr[t];
  float s = p.x + p.y, ss = p.x * p.x + p.y * p.y;
  for (int off = 32; off; off >>= 1){ s += __shfl_down(s, off); ss += __shfl_down(ss, off); }
  __shared__ float red[8];
  int w = t >> 6, lane = t & 63;
  if (!lane){ red[w] = s; red[4 + w] = ss; }
  __syncthreads();
  s  = red[0] + red[1] + red[2] + red[3];
  ss = red[4] + red[5] + red[6] + red[7];
  float m = s * (1.0f / 512.0f), var = ss * (1.0f / 512.0f) - m * m;
  float rs = rsqrtf(var + 1e-5f);
  float2 gv = ((const float2*)g)[t], bv = ((const float2*)b)[t];
  float r0 = (p.x - m) * rs * gv.x + bv.x;
  float r1 = (p.y - m) * rs * gv.y + bv.y;
  ((u32*)(xn + (int64_t)row * 512))[t] = (u32)f2bf(r0) | ((u32)f2bf(r1) << 16);
}

// ---------------- LayerNorm over 128 (bf16 in, f32 params, bf16 out) ----------------
__global__ __launch_bounds__(256) void k_ln2(const u16* __restrict__ u, const float* __restrict__ g,
                                             const float* __restrict__ b, u16* __restrict__ un){
  int row = blockIdx.x * 4 + (threadIdx.x >> 6);
  int lane = threadIdx.x & 63;
  const u32* ur = (const u32*)(u + (int64_t)row * 128);
  u32 pv = ur[lane];
  float a = bf2f((u16)(pv & 0xffff)), c = bf2f((u16)(pv >> 16));
  float s = a + c, ss = a * a + c * c;
  for (int off = 32; off; off >>= 1){ s += __shfl_xor(s, off); ss += __shfl_xor(ss, off); }
  float m = s * (1.0f / 128.0f), var = ss * (1.0f / 128.0f) - m * m;
  float rs = rsqrtf(var + 1e-5f);
  float2 gv = ((const float2*)g)[lane], bv = ((const float2*)b)[lane];
  float r0 = (a - m) * rs * gv.x + bv.x;
  float r1 = (c - m) * rs * gv.y + bv.y;
  ((u32*)(un + (int64_t)row * 128))[lane] = (u32)f2bf(r0) | ((u32)f2bf(r1) << 16);
}

// ---------------- transpose un[BL,128] -> unT[(b,c,h), i] [8192,512] ----------------
__global__ __launch_bounds__(256) void k_transpose(const u16* __restrict__ un, u16* __restrict__ unT){
  int bc = blockIdx.x >> 3, it = blockIdx.x & 7;
  int b = bc >> 4, cc = bc & 15;
  __shared__ __align__(16) u16 tile[64][128];
  const u16* src = un + ((int64_t)(b * 8192 + cc * 512 + it * 64)) * 128;
  int t = threadIdx.x;
  for (int p = 0; p < 4; p++){
    int id = p * 256 + t; int ri = id >> 4, seg = id & 15;
    *(U4*)&tile[ri][seg * 8] = *(const U4*)(src + (int64_t)ri * 128 + seg * 8);
  }
  __syncthreads();
  u16* dst = unT + ((int64_t)(bc * 128)) * 512 + it * 64;
  for (int p = 0; p < 4; p++){
    int id = p * 256 + t; int h = id >> 3, seg = id & 7;
    U4 pk; u16* pv = (u16*)&pk;
    for (int k2 = 0; k2 < 8; k2++) pv[k2] = tile[seg * 8 + k2][h];
    *(U4*)(dst + (int64_t)h * 512 + seg * 8) = pk;
  }
}

// ---------------- DSS tables (f32 params) ----------------
__global__ __launch_bounds__(512) void k_prep(const float* lam_re, const float* lam_im,
    const float* C_re, const float* C_im,
    u16* ZC, u16* PC, u16* VC, u16* ccat, float* cre, float* cim, float* zT){
  int n = blockIdx.x, t = threadIdx.x;
  float lr = -expf(lam_re[n]);
  float li =  expf(lam_im[n]);
  float mag = expf(lr * (float)t), ph = li * (float)t;
  float er = mag * cosf(ph), ei = mag * sinf(ph);
  ZC[(int64_t)n * 512 + (511 - t)]         = f2bf(er);
  ZC[(int64_t)(512 + n) * 512 + (511 - t)] = f2bf(ei);
  VC[(int64_t)t * 1024 + n]       = f2bf(er);
  VC[(int64_t)t * 1024 + 512 + n] = f2bf(-ei);
  float mag2 = expf(lr * (float)(t + 1)), ph2 = li * (float)(t + 1);
  PC[(int64_t)t * 1024 + n]       = f2bf(mag2 * cosf(ph2));
  PC[(int64_t)t * 1024 + 512 + n] = f2bf(-mag2 * sinf(ph2));
  if (t == 0){
    float m5 = expf(lr * 512.0f), p5 = li * 512.0f;
    zT[n] = m5 * cosf(p5); zT[512 + n] = m5 * sinf(p5);
  }
  if (t < 128){
    float e1m = expf(lr);
    float e1r = e1m * cosf(li), e1i = e1m * sinf(li);
    float nr = e1r - 1.0f, ni = e1i;
    float d2 = lr * lr + li * li;
    float qr = (nr * lr + ni * li) / d2, qi = (ni * lr - nr * li) / d2;
    float Cr = C_re[t * 512 + n], Ci = C_im[t * 512 + n];
    float vr = Cr * qr - Ci * qi, vi = Cr * qi + Ci * qr;
    cre[t * 512 + n] = vr; cim[t * 512 + n] = vi;
    ccat[(int64_t)t * 1024 + n] = f2bf(vr); ccat[(int64_t)t * 1024 + 512 + n] = f2bf(vi);
  }
}

// ---------------- kern[d,h] = sum_n VC[d,n]*ccat[h,n] (512x128, K=1024) ----------------
__global__ __launch_bounds__(128) void k_kern(const u16* __restrict__ VC,
                                              const u16* __restrict__ ccat,
                                              float* __restrict__ kern){
  __shared__ __align__(16) u16 vrow[1024];
  int d = blockIdx.x, h = threadIdx.x;
  *(U4*)&vrow[h * 8] = *(const U4*)(VC + (int64_t)d * 1024 + h * 8);
  __syncthreads();
  const u16* cr = ccat + (int64_t)h * 1024;
  float s = 0.0f;
  #pragma unroll 4
  for (int k = 0; k < 1024; k += 8){
    short8 a = *(const short8*)&vrow[k];
    short8 b = *(const short8*)(cr + k);
    #pragma unroll
    for (int j = 0; j < 8; j++) s += bf2f((u16)a[j]) * bf2f((u16)b[j]);
  }
  kern[(int64_t)d * 128 + h] = s;
}

// ---------------- block-Toeplitz build ----------------
__global__ __launch_bounds__(512) void k_rcat(const float* __restrict__ kern, u16* __restrict__ Rcat){
  int h = blockIdx.x >> 7, a = blockIdx.x & 127;
  int kcol = threadIdx.x;
  int d = 3 - (kcol >> 7);
  int delay = d * 128 + a - (kcol & 127);
  float val = (delay >= 0 && delay < 512) ? kern[delay * 128 + h] : 0.0f;
  Rcat[((int64_t)(h * 128 + a)) * 512 + kcol] = f2bf(val);
}

// ---------------- chunk scan + W = c * Scarry ----------------
__global__ __launch_bounds__(256) void k_scan(const float* __restrict__ S, const float* __restrict__ cre,
    const float* __restrict__ cim, const float* __restrict__ zT, u16* __restrict__ WT){
  int tid = blockIdx.x * 256 + threadIdx.x;   // 262144
  int n = tid & 511, bh = tid >> 9, b = bh >> 7, h = bh & 127;
  float cr = cre[h * 512 + n], ci = cim[h * 512 + n];
  float zr = zT[n], zi = zT[512 + n];
  float sR = 0.0f, sI = 0.0f;
  for (int cc = 0; cc < 16; cc++){
    int64_t m = (int64_t)(b * 16 + cc) * 128 + h;
    float wR = cr * sR - ci * sI, wI = cr * sI + ci * sR;
    WT[m * 1024 + n] = f2bf(wR);
    WT[m * 1024 + 512 + n] = f2bf(wI);
    float aR = S[m * 1024 + n], aI = S[m * 1024 + 512 + n];
    float nR = zr * sR - zi * sI + aR;
    sI = zr * sI + zi * sR + aI;
    sR = nR;
  }
}

// ---------------- y = Yloc + Ycross + un*D_skip (tiled, coalesced both sides) ----------------
__global__ __launch_bounds__(512) void k_assemble2(const float* __restrict__ Yloc,
    const float* __restrict__ Ycross, const u16* __restrict__ un,
    const float* __restrict__ Dskip, u16* __restrict__ y){
  __shared__ float tile[128][65];
  int ii = blockIdx.x;           // 0..511
  int t = threadIdx.x;
  int hl = t >> 6;               // 0..7
  int bcl = t & 63;
  #pragma unroll
  for (int p = 0; p < 16; p++){
    int h = p * 8 + hl;
    tile[h][bcl] = Yloc[((int64_t)(h * 512 + ii)) * 64 + bcl];
  }
  __syncthreads();
  int h = t & 127;
  int bcr = t >> 7;              // 0..3
  float dk = Dskip[h];
  #pragma unroll
  for (int p = 0; p < 16; p++){
    int bc = p * 4 + bcr;
    int b = bc >> 4, cc = bc & 15;
    int64_t e = ((int64_t)b * 8192 + cc * 512 + ii) * 128 + h;
    float val = tile[h][bc]
              + Ycross[(int64_t)ii * 8192 + (int64_t)bc * 128 + h]
              + bf2f(un[e]) * dk;
    y[e] = f2bf(val);
  }
}

// ---------------- generic BT GEMM: C[m,n] = sum_k A[m,k]*B[n,k] ----------------
// EPI: 0 = f32 direct store; 1 = gelu->bf16
// TRI: block-Toeplitz mode.
template<int EPI, bool TRI = false>
__global__ __launch_bounds__(256) void k_gemm(
    const u16* __restrict__ A, int64_t lda, int64_t aZ,
    const u16* __restrict__ B, int64_t ldb, int64_t bZ,
    void* Cp, int64_t ldc, int64_t cZ,
    int K, int Nvalid,
    const u16* aux1, const float* auxf1, const float* auxf2)
{
  __shared__ union __align__(16) SMU { u16 st[2][4096]; float ep[4][1088]; } sm;
  const int tid = threadIdx.x;
  const int lane = tid & 63, w = tid >> 6;
  const int wr = w >> 1, wc = w & 1, q = lane >> 4, c16 = lane & 15;
  const int sRow = lane >> 2, sSeg = lane & 3;
  const int z = blockIdx.z;

  int bx = blockIdx.x, by = blockIdx.y;
  if (!TRI && (gridDim.y & 7) == 0 && gridDim.x > 1){
    u32 idx = by * gridDim.x + bx;
    u32 xcd = idx & 7, s = idx >> 3;
    bx = s % gridDim.x;
    by = (s / gridDim.x) * 8 + xcd;
  }
  const int64_t m0 = (int64_t)by * 128;
  const int64_t n0 = (int64_t)bx * 128;

  const u16* Ab = A + (int64_t)z * aZ;
  const u16* Bp = B + (int64_t)z * bZ;
  int Keff = K;
  if (TRI){
    Ab += 384 - m0;              // (3-ib)*128 column shift
    Keff = (int)(m0 + 128);      // (ib+1)*128
  }

  v4f acc[4][4];
  #pragma unroll
  for (int i = 0; i < 4; i++)
    #pragma unroll
    for (int j = 0; j < 4; j++)
      acc[i][j] = (v4f)0.0f;

  for (int k0 = 0; k0 < Keff; k0 += 32){
    #pragma unroll
    for (int half = 0; half < 2; half++){
      int r0 = (half * 4 + w) * 16;
      int64_t arow = (TRI ? (int64_t)0 : m0) + r0 + sRow;
      ldsload16(Ab + arow * lda + k0 + sSeg * 8, &sm.st[0][r0 * 32]);
      int64_t brow = n0 + r0 + sRow;
      if (brow >= Nvalid) brow = Nvalid - 1;
      ldsload16(Bp + brow * ldb + k0 + sSeg * 8, &sm.st[1][r0 * 32]);
    }
    __syncthreads();
    short8 af[4], bfr[4];
    const u16* aB = &sm.st[0][(wr * 64 + c16) * 32 + q * 8];
    const u16* bB = &sm.st[1][(wc * 64 + c16) * 32 + q * 8];
    #pragma unroll
    for (int i = 0; i < 4; i++) af[i]  = *(const short8*)(aB + i * 512);
    #pragma unroll
    for (int j = 0; j < 4; j++) bfr[j] = *(const short8*)(bB + j * 512);
    #pragma unroll
    for (int i = 0; i < 4; i++)
      #pragma unroll
      for (int j = 0; j < 4; j++)
        acc[i][j] = __builtin_amdgcn_mfma_f32_16x16x32_bf16(af[i], bfr[j], acc[i][j], 0, 0, 0);
    __syncthreads();
  }

  if (EPI == 0){
    float* Cf = (float*)Cp + (int64_t)z * cZ;
    #pragma unroll
    for (int i = 0; i < 4; i++)
      #pragma unroll
      for (int j = 0; j < 4; j++){
        int64_t gr = m0 + wr * 64 + i * 16 + q * 4;
        int64_t gc = n0 + wc * 64 + j * 16 + c16;
        if (gc < Nvalid){
          #pragma unroll
          for (int r = 0; r < 4; r++)
            Cf[(gr + r) * ldc + gc] = acc[i][j][r];
        }
      }
    return;
  }

  // bf16 output path: per-wave LDS transpose for packed stores
  u16* Cb = (u16*)Cp + (int64_t)z * cZ;
  float* ep = sm.ep[w];
  for (int i = 0; i < 4; i++){
    #pragma unroll
    for (int j = 0; j < 4; j++)
      #pragma unroll
      for (int r = 0; r < 4; r++){
        float vv = acc[i][j][r];
        if (EPI == 1) vv = geluf(vv);
        ep[(q * 4 + r) * 68 + j * 16 + c16] = vv;
      }
    #pragma unroll
    for (int p = 0; p < 4; p++){
      int id = p * 64 + lane;
      int row = id >> 4, cg = id & 15;
      float o0 = ep[row * 68 + cg * 4 + 0];
      float o1 = ep[row * 68 + cg * 4 + 1];
      float o2 = ep[row * 68 + cg * 4 + 2];
      float o3 = ep[row * 68 + cg * 4 + 3];
      int64_t gr = m0 + wr * 64 + i * 16 + row;
      int64_t gc = n0 + wc * 64 + cg * 4;
      if (gc < Nvalid){
        U2 outp;
        outp.x = (u32)f2bf(o0) | ((u32)f2bf(o1) << 16);
        outp.y = (u32)f2bf(o2) | ((u32)f2bf(o3) << 16);
        *(U2*)(Cb + gr * ldc + gc) = outp;
      }
    }
  }
}

// ======= 256x256 GEMM, BK=32, 3-deep LDS ring, COUNTED vmcnt (T3+T4) =======
// C[m,n] = sum_k A[m,k]*B[n,k]; EPI: 0 = f32 out (+auxf1[m,n]+auxf2[n]),
// 1 = gelu -> bf16, 2 = *aux1[m,n](bf16) -> bf16.
// 512 threads = 8 waves (wr=wid>>2 picks 128-row half; wc=wid&3 picks 64-col
// strip). Per wave per tile: 12 ds_read_b128, 32 MFMA. LDS = 3 x 32KB buffers
// {A 16KB | B 16KB}; tile T stages T+2 into buf[(T+2)%3] (4 gload_lds/thread),
// computes T, then lgkmcnt(0) + vmcnt(4) (confirm T+1, keep T+2 in flight —
// NEVER drains to 0 mid-loop; m218's T4 lever) + barrier. Staging target was
// last read at tile T-1, whose reads retired before T-1's barrier -> race-free.
// Swizzle (64B rows, 4 chunks): physical chunk c at row r holds global chunk
// c ^ ((r>>1)&3); ds_read kx = (q ^ ((c16>>1)&3))<<4 -> uniform 8-access/bank.
// Requires: M%256==0, N%256==0, K%32==0, NT>=2.
#define FENCE __builtin_amdgcn_sched_barrier(0)
#define BARX  __builtin_amdgcn_s_barrier()

// one STAGE32 = one global_load_lds per thread; 8 waves cover 128 rows (SEL half)
#define STAGE32(SRC, LD, BUFO, OPO, SEL, KT)                                    \
  { const u16* _g = (SRC) + (int64_t)(KT) * 32 + (int64_t)((SEL) * 128 + wid * 16) * (LD); \
    u16* _lb = smd + (BUFO) + (OPO) + ((SEL) * 128 + wid * 16) * 32;            \
    ldsload16(_g, _lb); }

#define DO_T(T, CUR, FUT)                                                       \
  {                                                                             \
    if ((T) + 2 < NT){                                                          \
      STAGE32(Asrc, lda, (FUT), 0,    0, (T) + 2);                              \
      STAGE32(Asrc, lda, (FUT), 0,    1, (T) + 2);                              \
      STAGE32(Bsrc, ldb, (FUT), 8192, 0, (T) + 2);                              \
      STAGE32(Bsrc, ldb, (FUT), 8192, 1, (T) + 2);                              \
    }                                                                           \
    const char* Ac = (const char*)(smd + (CUR));                                \
    const char* Bc = (const char*)(smd + (CUR) + 8192);                         \
    _Pragma("unroll")                                                           \
    for (int mi = 0; mi < 8; mi++)                                              \
      af[mi] = *(const short8*)(Ac + abase + mi * 1024 + kx);                   \
    _Pragma("unroll")                                                           \
    for (int ni = 0; ni < 4; ni++)                                              \
      bf[ni] = *(const short8*)(Bc + bbase + ni * 1024 + kx);                   \
    __builtin_amdgcn_s_setprio(1);                                              \
    _Pragma("unroll")                                                           \
    for (int mi = 0; mi < 8; mi++)                                              \
      _Pragma("unroll")                                                         \
      for (int ni = 0; ni < 4; ni++)                                            \
        acc[mi][ni] = __builtin_amdgcn_mfma_f32_16x16x32_bf16(                  \
            af[mi], bf[ni], acc[mi][ni], 0, 0, 0);                              \
    __builtin_amdgcn_s_setprio(0);                                              \
    asm volatile("s_waitcnt lgkmcnt(0)" ::: "memory");                          \
    if ((T) + 2 < NT) asm volatile("s_waitcnt vmcnt(4)" ::: "memory");          \
    else              asm volatile("s_waitcnt vmcnt(0)" ::: "memory");          \
    FENCE; BARX; FENCE;                                                         \
  }

template<int EPI>
__global__ __launch_bounds__(512) void k_gemm256(
    const u16* __restrict__ A, int64_t lda,
    const u16* __restrict__ B, int64_t ldb,
    void* __restrict__ Cp, int64_t ldc, int K,
    const u16* __restrict__ aux1,
    const float* __restrict__ auxf1, const float* __restrict__ auxf2)
{
  extern __shared__ __align__(16) u16 smd[];   // 3 x 32KB = 96 KiB
  const int tid = threadIdx.x, wid = tid >> 6, lane = tid & 63;
  const int wr = wid >> 2, wc = wid & 3, c16 = lane & 15;
  const int q4 = (lane >> 4) << 2;

  int bx = blockIdx.x, by = blockIdx.y;        // bijective XCD swizzle
  if ((gridDim.y & 7) == 0 && gridDim.x > 1){
    u32 idx = by * gridDim.x + bx;
    u32 xcd = idx & 7, s = idx >> 3;
    bx = s % gridDim.x;
    by = (s / gridDim.x) * 8 + xcd;
  }
  const int64_t m0 = (int64_t)by * 256;
  const int64_t n0 = (int64_t)bx * 256;
  const int NT = K >> 5;                       // BK=32

  // staging lane geometry: 16 rows x 64B per wave-instruction, chunk-swizzled
  const int rowin = lane >> 2;                          // 0..15
  const int chnk  = (lane & 3) ^ ((rowin >> 1) & 3);    // global 16B chunk
  const int colel = chnk * 8;                           // u16 elems
  const u16* Asrc = A + (m0 + rowin) * lda + colel;
  const u16* Bsrc = B + (n0 + rowin) * ldb + colel;

  // ds_read: row*64B + kx, kx = (q ^ ((c16>>1)&3))<<4
  const int kx = (((lane >> 4) ^ ((c16 >> 1) & 3)) << 4);
  const int abase = (wr * 128 + c16) * 64;     // A row bytes (mi=0)
  const int bbase = (wc * 64 + c16) * 64;      // B row bytes (ni=0)

  v4f acc[8][4];
  #pragma unroll
  for (int i = 0; i < 8; i++)
    #pragma unroll
    for (int j = 0; j < 4; j++) acc[i][j] = (v4f)0.0f;

  short8 af[8], bf[4];

  // prologue: stage tile0 -> buf0, tile1 -> buf1; confirm tile0 (vmcnt(4)),
  // leave tile1's 4 loads in flight -> steady-state invariant.
  STAGE32(Asrc, lda, 0, 0,    0, 0);
  STAGE32(Asrc, lda, 0, 0,    1, 0);
  STAGE32(Bsrc, ldb, 0, 8192, 0, 0);
  STAGE32(Bsrc, ldb, 0, 8192, 1, 0);
  if (NT > 1){
    STAGE32(Asrc, lda, 16384, 0,    0, 1);
    STAGE32(Asrc, lda, 16384, 0,    1, 1);
    STAGE32(Bsrc, ldb, 16384, 8192, 0, 1);
    STAGE32(Bsrc, ldb, 16384, 8192, 1, 1);
    asm volatile("s_waitcnt vmcnt(4)" ::: "memory");
  } else {
    asm volatile("s_waitcnt vmcnt(0)" ::: "memory");
  }
  FENCE; BARX; FENCE;

  int cur = 0, nxt = 16384, fut = 32768;       // u16-elem buffer offsets
  for (int t = 0; t < NT; ++t){
    DO_T(t, cur, fut)
    int tmp = cur; cur = nxt; nxt = fut; fut = tmp;
  }

  if (EPI == 0){
    // epilogue: C = acc + auxf1 + auxf2 (f32)
    float* C = (float*)Cp;
    #pragma unroll
    for (int mi = 0; mi < 8; mi++){
      int64_t gr = m0 + wr * 128 + mi * 16 + q4;
      #pragma unroll
      for (int ni = 0; ni < 4; ni++){
        int64_t gc = n0 + wc * 64 + ni * 16 + c16;
        v4f a = acc[mi][ni];
        float bo = auxf2[gc];
        #pragma unroll
        for (int r = 0; r < 4; r++)
          C[(gr + r) * ldc + gc] = a[r] + auxf1[(gr + r) * ldc + gc] + bo;
      }
    }
    return;
  }

  // bf16 epilogue: per-wave LDS transpose (16x33 f32 scratch), packed 16B
  // stores. Buffers are dead after the final tile barrier.
  u16* Cb = (u16*)Cp;
  float* scr = (float*)smd + wid * 528;
  const int erow = lane >> 2, eseg = lane & 3;
  #pragma unroll
  for (int mi = 0; mi < 8; mi++){
    #pragma unroll
    for (int nh = 0; nh < 2; nh++){
      #pragma unroll
      for (int ni = 0; ni < 2; ni++){
        v4f a = acc[mi][nh * 2 + ni];
        #pragma unroll
        for (int r = 0; r < 4; r++){
          float vv = a[r];
          if (EPI == 1) vv = geluf(vv);
          scr[(q4 + r) * 33 + ni * 16 + c16] = vv;
        }
      }
      float o[8];
      #pragma unroll
      for (int kq = 0; kq < 8; kq++) o[kq] = scr[erow * 33 + eseg * 8 + kq];
      int64_t gr = m0 + wr * 128 + mi * 16 + erow;
      int64_t gc = n0 + wc * 64 + nh * 32 + eseg * 8;
      if (EPI == 2){
        U4 pv = *(const U4*)(aux1 + gr * ldc + gc);
        const u16* pp = (const u16*)&pv;
        #pragma unroll
        for (int kq = 0; kq < 8; kq++) o[kq] *= bf2f(pp[kq]);
      }
      U4 outp; u16* op = (u16*)&outp;
      #pragma unroll
      for (int kq = 0; kq < 8; kq++) op[kq] = f2bf(o[kq]);
      *(U4*)(Cb + gr * ldc + gc) = outp;
    }
  }
}

extern "C" void kernel_launch(void* const* d_in, const int* in_sizes, int n_in,
                              void* d_out, int out_size, void* d_ws, size_t ws_size,
                              hipStream_t stream) {
  (void)in_sizes; (void)n_in; (void)out_size; (void)ws_size;
  const float* x      = (const float*)d_in[0];
  const float* norm_g = (const float*)d_in[1];
  const float* norm_b = (const float*)d_in[2];
  const float* W_v    = (const float*)d_in[3];
  const float* W_u    = (const float*)d_in[4];
  const float* W_uc   = (const float*)d_in[5];
  const float* W_o    = (const float*)d_in[6];
  const float* b_o    = (const float*)d_in[7];
  const float* dss_g  = (const float*)d_in[8];
  const float* dss_b  = (const float*)d_in[9];
  const float* lam_re = (const float*)d_in[10];
  const float* lam_im = (const float*)d_in[11];
  const float* C_re   = (const float*)d_in[12];
  const float* C_im   = (const float*)d_in[13];
  const float* D_skip = (const float*)d_in[14];

  // ---- d_out (67.1 MB f32) doubles as scratch for xn + 2 bf16 weights (dead before final GEMM) ----
  char* ob = (char*)d_out;
  u16* xn    = (u16*)(ob);                         // 33,554,432 B
  u16* Wv_b  = (u16*)(ob + 33554432ull);           //  2,097,152 B
  u16* Wu_b  = (u16*)(ob + 35651584ull);           //    131,072 B

  // ---- workspace layout (aliased by lifetime), total ~224 MiB ----
  char* ws = (char*)d_ws;
  const size_t R1      = 134217728ull;             // after v: u -> (Rcat | WT)
  const size_t OFF_UN  = R1 + 33554432ull;
  const size_t OFF_UNT = OFF_UN + 8388608ull;      // unT, later y
  const size_t OFF_R2  = OFF_UNT + 8388608ull;     // S -> (Ycross | Yloc)
  const size_t OFF_TAB = OFF_R2 + 33554432ull;

  u16*  v     = (u16*)(ws + 0);                    // [32768,2048] bf16
  u16*  u     = (u16*)(ws + R1);
  u16*  Rcat  = (u16*)(ws + R1);                   // 16.8 MB
  u16*  WT    = (u16*)(ws + R1 + 16777216ull);     // 16.8 MB
  u16*  un    = (u16*)(ws + OFF_UN);
  u16*  unT   = (u16*)(ws + OFF_UNT);
  u16*  y     = (u16*)(ws + OFF_UNT);
  float* S    = (float*)(ws + OFF_R2);
  float* Ycross = (float*)(ws + OFF_R2);
  float* Yloc = (float*)(ws + OFF_R2 + 16777216ull);
  char* tp = ws + OFF_TAB;
  u16*  ZC   = (u16*)tp;            tp += 1048576;
  u16*  PC   = (u16*)tp;            tp += 1048576;
  u16*  VC   = (u16*)tp;            tp += 1048576;
  u16*  ccat = (u16*)tp;            tp += 262144;
  float* cre = (float*)tp;          tp += 262144;
  float* cim = (float*)tp;          tp += 262144;
  float* zT  = (float*)tp;          tp += 4096;
  float* kern= (float*)tp;          tp += 262144;
  u16*  Wo_b = (u16*)tp;            tp += 2097152;
  u16*  Wuc_b= (u16*)tp;            tp += 524288;

  // weight conversions (f32 -> bf16), one launch
  k_cvt4<<<9472, 256, 0, stream>>>(W_v, Wv_b, 2048 * 512,
                                   W_u, Wu_b, 128 * 512,
                                   W_uc, Wuc_b, 2048 * 128,
                                   W_o, Wo_b, 512 * 2048);

  k_ln1<<<BL, 256, 0, stream>>>(x, norm_g, norm_b, xn);
  k_prep<<<512, 512, 0, stream>>>(lam_re, lam_im, C_re, C_im, ZC, PC, VC, ccat, cre, cim, zT);
  // kern while VC/ccat are L2-hot
  k_kern<<<512, 128, 0, stream>>>(VC, ccat, kern);

  // v = gelu(xn @ W_v^T)   [32768,2048] bf16 -- 3-ring counted-vmcnt kernel
  k_gemm256<1><<<dim3(8, 128), 512, 98304, stream>>>(xn, 512, Wv_b, 512, v, 2048, 512, nullptr, nullptr, nullptr);
  // u = gelu(xn @ W_u^T)   [32768,128] bf16 (N=128 -> old template)
  k_gemm<1><<<dim3(1, 256, 1), 256, 0, stream>>>(xn, 512, 0, Wu_b, 512, 0, u, 128, 0, 512, 128, nullptr, nullptr, nullptr);
  k_ln2<<<BL / 4, 256, 0, stream>>>(u, dss_g, dss_b, un);
  k_transpose<<<512, 256, 0, stream>>>(un, unT);

  k_rcat<<<16384, 512, 0, stream>>>(kern, Rcat);

  // chunk states: S[m,n'] = sum_i unT[m,i]*ZC[n',i]  [8192,1024] f32
  k_gemm<0><<<dim3(8, 64, 1), 256, 0, stream>>>(unT, 512, 0, ZC, 512, 0, S, 1024, 0, 512, 1024, nullptr, nullptr, nullptr);
  k_scan<<<1024, 256, 0, stream>>>(S, cre, cim, zT, WT);
  // injection: Ycross[i,m] = sum_n' PC[i,n']*WT[m,n']  [512,8192] f32
  k_gemm<0><<<dim3(64, 4, 1), 256, 0, stream>>>(PC, 1024, 0, WT, 1024, 0, Ycross, 8192, 0, 1024, 8192, nullptr, nullptr, nullptr);
  // local conv via block-Toeplitz, single launch (TRI mode: by = i_blk)
  k_gemm<0, true><<<dim3(1, 4, 128), 256, 0, stream>>>(
      Rcat, 512, 65536, unT, 65536, 512, Yloc, 64, 32768, 512, 64, nullptr, nullptr, nullptr);
  // y assembled with coalesced Yloc reads (LDS transpose per ii)
  k_assemble2<<<512, 512, 0, stream>>>(Yloc, Ycross, un, D_skip, y);

  // uc = y @ W_uc^T, fused t = uc*v (in place over v)
  k_gemm256<2><<<dim3(8, 128), 512, 98304, stream>>>(y, 128, Wuc_b, 128, v, 2048, 128, v, nullptr, nullptr);
  // out = t @ W_o^T + b_o + x   (f32 out)
  k_gemm256<0><<<dim3(2, 128), 512, 98304, stream>>>(v, 2048, Wo_b, 2048, d_out, 512, 2048, nullptr, x, b_o);
}

// Round 8
// 553.347 us; speedup vs baseline: 1.1050x; 1.0922x over previous
//
#include <hip/hip_runtime.h>
#include <math.h>
#include <stdint.h>

typedef unsigned short u16;
typedef unsigned int   u32;
typedef short short8 __attribute__((ext_vector_type(8)));
typedef float v4f    __attribute__((ext_vector_type(4)));

#define DEVI static __device__ __forceinline__

struct __align__(8)  U2 { u32 x, y; };
struct __align__(16) U4 { u32 x, y, z, w; };

static const int BB = 4, LL = 8192;
static const int BL = BB * LL;           // 32768 rows

DEVI float bf2f(u16 u){ u32 v = ((u32)u) << 16; float f; __builtin_memcpy(&f, &v, 4); return f; }
DEVI u16  f2bf(float f){ u32 u; __builtin_memcpy(&u, &f, 4); return (u16)((u + 0x7fffu + ((u >> 16) & 1u)) >> 16); }

// fast exact-gelu: erf via Abramowitz-Stegun 7.1.26 (max abs err 1.5e-7,
// far below bf16 rounding). ~15 VALU vs libm erff's ~100+.
DEVI float geluf(float x){
  float z = fabsf(x) * 0.7071067811865475f;
  float t = __builtin_amdgcn_rcpf(1.0f + 0.3275911f * z);
  float p = t * (0.254829592f + t * (-0.284496736f + t * (1.421413741f +
            t * (-1.453152027f + t * 1.061405429f))));
  float e = __builtin_amdgcn_exp2f(z * z * -1.4426950408889634f);
  float er = 1.0f - p * e;
  float s = (x < 0.0f) ? -er : er;
  return 0.5f * x * (1.0f + s);
}

DEVI void ldsload16(const void* g, void* l){
  __builtin_amdgcn_global_load_lds(
      (const __attribute__((address_space(1))) u32*)(uintptr_t)g,
      (__attribute__((address_space(3)))  u32*)(u32)(uintptr_t)l,
      16, 0, 0);
}

// ---------------- f32 -> bf16 convert, 4 tensors in one launch ----------------
__global__ __launch_bounds__(256) void k_cvt4(
    const float* __restrict__ s0, u16* __restrict__ d0, int n0,
    const float* __restrict__ s1, u16* __restrict__ d1, int n1,
    const float* __restrict__ s2, u16* __restrict__ d2, int n2,
    const float* __restrict__ s3, u16* __restrict__ d3, int n3){
  int i = blockIdx.x * 256 + threadIdx.x;
  if (i < n0){ d0[i] = f2bf(s0[i]); return; }
  i -= n0;
  if (i < n1){ d1[i] = f2bf(s1[i]); return; }
  i -= n1;
  if (i < n2){ d2[i] = f2bf(s2[i]); return; }
  i -= n2;
  if (i < n3){ d3[i] = f2bf(s3[i]); }
}

// ---------------- LayerNorm over 512 (f32 in, bf16 out) ----------------
__global__ __launch_bounds__(256) void k_ln1(const float* __restrict__ x, const float* __restrict__ g,
                                             const float* __restrict__ b, u16* __restrict__ xn){
  int row = blockIdx.x, t = threadIdx.x;
  const float2* xr = (const float2*)(x + (int64_t)row * 512);
  float2 p = xr[t];
  float s = p.x + p.y, ss = p.x * p.x + p.y * p.y;
  for (int off = 32; off; off >>= 1){ s += __shfl_down(s, off); ss += __shfl_down(ss, off); }
  __shared__ float red[8];
  int w = t >> 6, lane = t & 63;
  if (!lane){ red[w] = s; red[4 + w] = ss; }
  __syncthreads();
  s  = red[0] + red[1] + red[2] + red[3];
  ss = red[4] + red[5] + red[6] + red[7];
  float m = s * (1.0f / 512.0f), var = ss * (1.0f / 512.0f) - m * m;
  float rs = rsqrtf(var + 1e-5f);
  float2 gv = ((const float2*)g)[t], bv = ((const float2*)b)[t];
  float r0 = (p.x - m) * rs * gv.x + bv.x;
  float r1 = (p.y - m) * rs * gv.y + bv.y;
  ((u32*)(xn + (int64_t)row * 512))[t] = (u32)f2bf(r0) | ((u32)f2bf(r1) << 16);
}

// ---------------- LayerNorm over 128 (bf16 in, f32 params, bf16 out) ----------------
__global__ __launch_bounds__(256) void k_ln2(const u16* __restrict__ u, const float* __restrict__ g,
                                             const float* __restrict__ b, u16* __restrict__ un){
  int row = blockIdx.x * 4 + (threadIdx.x >> 6);
  int lane = threadIdx.x & 63;
  const u32* ur = (const u32*)(u + (int64_t)row * 128);
  u32 pv = ur[lane];
  float a = bf2f((u16)(pv & 0xffff)), c = bf2f((u16)(pv >> 16));
  float s = a + c, ss = a * a + c * c;
  for (int off = 32; off; off >>= 1){ s += __shfl_xor(s, off); ss += __shfl_xor(ss, off); }
  float m = s * (1.0f / 128.0f), var = ss * (1.0f / 128.0f) - m * m;
  float rs = rsqrtf(var + 1e-5f);
  float2 gv = ((const float2*)g)[lane], bv = ((const float2*)b)[lane];
  float r0 = (a - m) * rs * gv.x + bv.x;
  float r1 = (c - m) * rs * gv.y + bv.y;
  ((u32*)(un + (int64_t)row * 128))[lane] = (u32)f2bf(r0) | ((u32)f2bf(r1) << 16);
}

// ---------------- transpose un[BL,128] -> unT[(b,c,h), i] [8192,512] ----------------
__global__ __launch_bounds__(256) void k_transpose(const u16* __restrict__ un, u16* __restrict__ unT){
  int bc = blockIdx.x >> 3, it = blockIdx.x & 7;
  int b = bc >> 4, cc = bc & 15;
  __shared__ __align__(16) u16 tile[64][128];
  const u16* src = un + ((int64_t)(b * 8192 + cc * 512 + it * 64)) * 128;
  int t = threadIdx.x;
  for (int p = 0; p < 4; p++){
    int id = p * 256 + t; int ri = id >> 4, seg = id & 15;
    *(U4*)&tile[ri][seg * 8] = *(const U4*)(src + (int64_t)ri * 128 + seg * 8);
  }
  __syncthreads();
  u16* dst = unT + ((int64_t)(bc * 128)) * 512 + it * 64;
  for (int p = 0; p < 4; p++){
    int id = p * 256 + t; int h = id >> 3, seg = id & 7;
    U4 pk; u16* pv = (u16*)&pk;
    for (int k2 = 0; k2 < 8; k2++) pv[k2] = tile[seg * 8 + k2][h];
    *(U4*)(dst + (int64_t)h * 512 + seg * 8) = pk;
  }
}

// ---------------- DSS tables (f32 params) ----------------
__global__ __launch_bounds__(512) void k_prep(const float* lam_re, const float* lam_im,
    const float* C_re, const float* C_im,
    u16* ZC, u16* PC, u16* VC, u16* ccat, float* cre, float* cim, float* zT){
  int n = blockIdx.x, t = threadIdx.x;
  float lr = -expf(lam_re[n]);
  float li =  expf(lam_im[n]);
  float mag = expf(lr * (float)t), ph = li * (float)t;
  float er = mag * cosf(ph), ei = mag * sinf(ph);
  ZC[(int64_t)n * 512 + (511 - t)]         = f2bf(er);
  ZC[(int64_t)(512 + n) * 512 + (511 - t)] = f2bf(ei);
  VC[(int64_t)t * 1024 + n]       = f2bf(er);
  VC[(int64_t)t * 1024 + 512 + n] = f2bf(-ei);
  float mag2 = expf(lr * (float)(t + 1)), ph2 = li * (float)(t + 1);
  PC[(int64_t)t * 1024 + n]       = f2bf(mag2 * cosf(ph2));
  PC[(int64_t)t * 1024 + 512 + n] = f2bf(-mag2 * sinf(ph2));
  if (t == 0){
    float m5 = expf(lr * 512.0f), p5 = li * 512.0f;
    zT[n] = m5 * cosf(p5); zT[512 + n] = m5 * sinf(p5);
  }
  if (t < 128){
    float e1m = expf(lr);
    float e1r = e1m * cosf(li), e1i = e1m * sinf(li);
    float nr = e1r - 1.0f, ni = e1i;
    float d2 = lr * lr + li * li;
    float qr = (nr * lr + ni * li) / d2, qi = (ni * lr - nr * li) / d2;
    float Cr = C_re[t * 512 + n], Ci = C_im[t * 512 + n];
    float vr = Cr * qr - Ci * qi, vi = Cr * qi + Ci * qr;
    cre[t * 512 + n] = vr; cim[t * 512 + n] = vi;
    ccat[(int64_t)t * 1024 + n] = f2bf(vr); ccat[(int64_t)t * 1024 + 512 + n] = f2bf(vi);
  }
}

// ---------------- kern[d,h] = sum_n VC[d,n]*ccat[h,n] (512x128, K=1024) ----------------
__global__ __launch_bounds__(128) void k_kern(const u16* __restrict__ VC,
                                              const u16* __restrict__ ccat,
                                              float* __restrict__ kern){
  __shared__ __align__(16) u16 vrow[1024];
  int d = blockIdx.x, h = threadIdx.x;
  *(U4*)&vrow[h * 8] = *(const U4*)(VC + (int64_t)d * 1024 + h * 8);
  __syncthreads();
  const u16* cr = ccat + (int64_t)h * 1024;
  float s = 0.0f;
  #pragma unroll 4
  for (int k = 0; k < 1024; k += 8){
    short8 a = *(const short8*)&vrow[k];
    short8 b = *(const short8*)(cr + k);
    #pragma unroll
    for (int j = 0; j < 8; j++) s += bf2f((u16)a[j]) * bf2f((u16)b[j]);
  }
  kern[(int64_t)d * 128 + h] = s;
}

// ---------------- block-Toeplitz build ----------------
__global__ __launch_bounds__(512) void k_rcat(const float* __restrict__ kern, u16* __restrict__ Rcat){
  int h = blockIdx.x >> 7, a = blockIdx.x & 127;
  int kcol = threadIdx.x;
  int d = 3 - (kcol >> 7);
  int delay = d * 128 + a - (kcol & 127);
  float val = (delay >= 0 && delay < 512) ? kern[delay * 128 + h] : 0.0f;
  Rcat[((int64_t)(h * 128 + a)) * 512 + kcol] = f2bf(val);
}

// ---------------- chunk scan + W = c * Scarry ----------------
__global__ __launch_bounds__(256) void k_scan(const float* __restrict__ S, const float* __restrict__ cre,
    const float* __restrict__ cim, const float* __restrict__ zT, u16* __restrict__ WT){
  int tid = blockIdx.x * 256 + threadIdx.x;   // 262144
  int n = tid & 511, bh = tid >> 9, b = bh >> 7, h = bh & 127;
  float cr = cre[h * 512 + n], ci = cim[h * 512 + n];
  float zr = zT[n], zi = zT[512 + n];
  float sR = 0.0f, sI = 0.0f;
  for (int cc = 0; cc < 16; cc++){
    int64_t m = (int64_t)(b * 16 + cc) * 128 + h;
    float wR = cr * sR - ci * sI, wI = cr * sI + ci * sR;
    WT[m * 1024 + n] = f2bf(wR);
    WT[m * 1024 + 512 + n] = f2bf(wI);
    float aR = S[m * 1024 + n], aI = S[m * 1024 + 512 + n];
    float nR = zr * sR - zi * sI + aR;
    sI = zr * sI + zi * sR + aI;
    sR = nR;
  }
}

// ---------------- y = Yloc + Ycross + un*D_skip (tiled, coalesced both sides) ----------------
__global__ __launch_bounds__(512) void k_assemble2(const float* __restrict__ Yloc,
    const float* __restrict__ Ycross, const u16* __restrict__ un,
    const float* __restrict__ Dskip, u16* __restrict__ y){
  __shared__ float tile[128][65];
  int ii = blockIdx.x;           // 0..511
  int t = threadIdx.x;
  int hl = t >> 6;               // 0..7
  int bcl = t & 63;
  #pragma unroll
  for (int p = 0; p < 16; p++){
    int h = p * 8 + hl;
    tile[h][bcl] = Yloc[((int64_t)(h * 512 + ii)) * 64 + bcl];
  }
  __syncthreads();
  int h = t & 127;
  int bcr = t >> 7;              // 0..3
  float dk = Dskip[h];
  #pragma unroll
  for (int p = 0; p < 16; p++){
    int bc = p * 4 + bcr;
    int b = bc >> 4, cc = bc & 15;
    int64_t e = ((int64_t)b * 8192 + cc * 512 + ii) * 128 + h;
    float val = tile[h][bc]
              + Ycross[(int64_t)ii * 8192 + (int64_t)bc * 128 + h]
              + bf2f(un[e]) * dk;
    y[e] = f2bf(val);
  }
}

// ---------------- generic BT GEMM: C[m,n] = sum_k A[m,k]*B[n,k] ----------------
// EPI: 0 = f32 direct store; 1 = gelu->bf16
// TRI: block-Toeplitz mode.
template<int EPI, bool TRI = false>
__global__ __launch_bounds__(256) void k_gemm(
    const u16* __restrict__ A, int64_t lda, int64_t aZ,
    const u16* __restrict__ B, int64_t ldb, int64_t bZ,
    void* Cp, int64_t ldc, int64_t cZ,
    int K, int Nvalid,
    const u16* aux1, const float* auxf1, const float* auxf2)
{
  __shared__ union __align__(16) SMU { u16 st[2][4096]; float ep[4][1088]; } sm;
  const int tid = threadIdx.x;
  const int lane = tid & 63, w = tid >> 6;
  const int wr = w >> 1, wc = w & 1, q = lane >> 4, c16 = lane & 15;
  const int sRow = lane >> 2, sSeg = lane & 3;
  const int z = blockIdx.z;

  int bx = blockIdx.x, by = blockIdx.y;
  if (!TRI && (gridDim.y & 7) == 0 && gridDim.x > 1){
    u32 idx = by * gridDim.x + bx;
    u32 xcd = idx & 7, s = idx >> 3;
    bx = s % gridDim.x;
    by = (s / gridDim.x) * 8 + xcd;
  }
  const int64_t m0 = (int64_t)by * 128;
  const int64_t n0 = (int64_t)bx * 128;

  const u16* Ab = A + (int64_t)z * aZ;
  const u16* Bp = B + (int64_t)z * bZ;
  int Keff = K;
  if (TRI){
    Ab += 384 - m0;              // (3-ib)*128 column shift
    Keff = (int)(m0 + 128);      // (ib+1)*128
  }

  v4f acc[4][4];
  #pragma unroll
  for (int i = 0; i < 4; i++)
    #pragma unroll
    for (int j = 0; j < 4; j++)
      acc[i][j] = (v4f)0.0f;

  for (int k0 = 0; k0 < Keff; k0 += 32){
    #pragma unroll
    for (int half = 0; half < 2; half++){
      int r0 = (half * 4 + w) * 16;
      int64_t arow = (TRI ? (int64_t)0 : m0) + r0 + sRow;
      ldsload16(Ab + arow * lda + k0 + sSeg * 8, &sm.st[0][r0 * 32]);
      int64_t brow = n0 + r0 + sRow;
      if (brow >= Nvalid) brow = Nvalid - 1;
      ldsload16(Bp + brow * ldb + k0 + sSeg * 8, &sm.st[1][r0 * 32]);
    }
    __syncthreads();
    short8 af[4], bfr[4];
    const u16* aB = &sm.st[0][(wr * 64 + c16) * 32 + q * 8];
    const u16* bB = &sm.st[1][(wc * 64 + c16) * 32 + q * 8];
    #pragma unroll
    for (int i = 0; i < 4; i++) af[i]  = *(const short8*)(aB + i * 512);
    #pragma unroll
    for (int j = 0; j < 4; j++) bfr[j] = *(const short8*)(bB + j * 512);
    #pragma unroll
    for (int i = 0; i < 4; i++)
      #pragma unroll
      for (int j = 0; j < 4; j++)
        acc[i][j] = __builtin_amdgcn_mfma_f32_16x16x32_bf16(af[i], bfr[j], acc[i][j], 0, 0, 0);
    __syncthreads();
  }

  if (EPI == 0){
    float* Cf = (float*)Cp + (int64_t)z * cZ;
    #pragma unroll
    for (int i = 0; i < 4; i++)
      #pragma unroll
      for (int j = 0; j < 4; j++){
        int64_t gr = m0 + wr * 64 + i * 16 + q * 4;
        int64_t gc = n0 + wc * 64 + j * 16 + c16;
        if (gc < Nvalid){
          #pragma unroll
          for (int r = 0; r < 4; r++)
            Cf[(gr + r) * ldc + gc] = acc[i][j][r];
        }
      }
    return;
  }

  // bf16 output path: per-wave LDS transpose for packed stores
  u16* Cb = (u16*)Cp + (int64_t)z * cZ;
  float* ep = sm.ep[w];
  for (int i = 0; i < 4; i++){
    #pragma unroll
    for (int j = 0; j < 4; j++)
      #pragma unroll
      for (int r = 0; r < 4; r++){
        float vv = acc[i][j][r];
        if (EPI == 1) vv = geluf(vv);
        ep[(q * 4 + r) * 68 + j * 16 + c16] = vv;
      }
    #pragma unroll
    for (int p = 0; p < 4; p++){
      int id = p * 64 + lane;
      int row = id >> 4, cg = id & 15;
      float o0 = ep[row * 68 + cg * 4 + 0];
      float o1 = ep[row * 68 + cg * 4 + 1];
      float o2 = ep[row * 68 + cg * 4 + 2];
      float o3 = ep[row * 68 + cg * 4 + 3];
      int64_t gr = m0 + wr * 64 + i * 16 + row;
      int64_t gc = n0 + wc * 64 + cg * 4;
      if (gc < Nvalid){
        U2 outp;
        outp.x = (u32)f2bf(o0) | ((u32)f2bf(o1) << 16);
        outp.y = (u32)f2bf(o2) | ((u32)f2bf(o3) << 16);
        *(U2*)(Cb + gr * ldc + gc) = outp;
      }
    }
  }
}

// ======= 256x256 GEMM, BK=32, 3-deep LDS ring, COUNTED vmcnt (T3+T4) =======
// (validated r7; used for the final GEMM. EPI: 0 = f32 out + auxf1 + auxf2.)
#define FENCE __builtin_amdgcn_sched_barrier(0)
#define BARX  __builtin_amdgcn_s_barrier()

#define STAGE32(SRC, LD, BUFO, OPO, SEL, KT)                                    \
  { const u16* _g = (SRC) + (int64_t)(KT) * 32 + (int64_t)((SEL) * 128 + wid * 16) * (LD); \
    u16* _lb = smd + (BUFO) + (OPO) + ((SEL) * 128 + wid * 16) * 32;            \
    ldsload16(_g, _lb); }

#define DO_T(T, CUR, FUT)                                                       \
  {                                                                             \
    if ((T) + 2 < NT){                                                          \
      STAGE32(Asrc, lda, (FUT), 0,    0, (T) + 2);                              \
      STAGE32(Asrc, lda, (FUT), 0,    1, (T) + 2);                              \
      STAGE32(Bsrc, ldb, (FUT), 8192, 0, (T) + 2);                              \
      STAGE32(Bsrc, ldb, (FUT), 8192, 1, (T) + 2);                              \
    }                                                                           \
    const char* Ac = (const char*)(smd + (CUR));                                \
    const char* Bc = (const char*)(smd + (CUR) + 8192);                         \
    _Pragma("unroll")                                                           \
    for (int mi = 0; mi < 8; mi++)                                              \
      af[mi] = *(const short8*)(Ac + abase + mi * 1024 + kx);                   \
    _Pragma("unroll")                                                           \
    for (int ni = 0; ni < 4; ni++)                                              \
      bf[ni] = *(const short8*)(Bc + bbase + ni * 1024 + kx);                   \
    __builtin_amdgcn_s_setprio(1);                                              \
    _Pragma("unroll")                                                           \
    for (int mi = 0; mi < 8; mi++)                                              \
      _Pragma("unroll")                                                         \
      for (int ni = 0; ni < 4; ni++)                                            \
        acc[mi][ni] = __builtin_amdgcn_mfma_f32_16x16x32_bf16(                  \
            af[mi], bf[ni], acc[mi][ni], 0, 0, 0);                              \
    __builtin_amdgcn_s_setprio(0);                                              \
    asm volatile("s_waitcnt lgkmcnt(0)" ::: "memory");                          \
    if ((T) + 2 < NT) asm volatile("s_waitcnt vmcnt(4)" ::: "memory");          \
    else              asm volatile("s_waitcnt vmcnt(0)" ::: "memory");          \
    FENCE; BARX; FENCE;                                                         \
  }

template<int EPI>
__global__ __launch_bounds__(512) void k_gemm256(
    const u16* __restrict__ A, int64_t lda,
    const u16* __restrict__ B, int64_t ldb,
    void* __restrict__ Cp, int64_t ldc, int K,
    const u16* __restrict__ aux1,
    const float* __restrict__ auxf1, const float* __restrict__ auxf2)
{
  extern __shared__ __align__(16) u16 smd[];   // 3 x 32KB = 96 KiB
  const int tid = threadIdx.x, wid = tid >> 6, lane = tid & 63;
  const int wr = wid >> 2, wc = wid & 3, c16 = lane & 15;
  const int q4 = (lane >> 4) << 2;

  int bx = blockIdx.x, by = blockIdx.y;        // bijective XCD swizzle
  if ((gridDim.y & 7) == 0 && gridDim.x > 1){
    u32 idx = by * gridDim.x + bx;
    u32 xcd = idx & 7, s = idx >> 3;
    bx = s % gridDim.x;
    by = (s / gridDim.x) * 8 + xcd;
  }
  const int64_t m0 = (int64_t)by * 256;
  const int64_t n0 = (int64_t)bx * 256;
  const int NT = K >> 5;                       // BK=32

  const int rowin = lane >> 2;                          // 0..15
  const int chnk  = (lane & 3) ^ ((rowin >> 1) & 3);    // global 16B chunk
  const int colel = chnk * 8;                           // u16 elems
  const u16* Asrc = A + (m0 + rowin) * lda + colel;
  const u16* Bsrc = B + (n0 + rowin) * ldb + colel;

  const int kx = (((lane >> 4) ^ ((c16 >> 1) & 3)) << 4);
  const int abase = (wr * 128 + c16) * 64;     // A row bytes (mi=0)
  const int bbase = (wc * 64 + c16) * 64;      // B row bytes (ni=0)

  v4f acc[8][4];
  #pragma unroll
  for (int i = 0; i < 8; i++)
    #pragma unroll
    for (int j = 0; j < 4; j++) acc[i][j] = (v4f)0.0f;

  short8 af[8], bf[4];

  STAGE32(Asrc, lda, 0, 0,    0, 0);
  STAGE32(Asrc, lda, 0, 0,    1, 0);
  STAGE32(Bsrc, ldb, 0, 8192, 0, 0);
  STAGE32(Bsrc, ldb, 0, 8192, 1, 0);
  if (NT > 1){
    STAGE32(Asrc, lda, 16384, 0,    0, 1);
    STAGE32(Asrc, lda, 16384, 0,    1, 1);
    STAGE32(Bsrc, ldb, 16384, 8192, 0, 1);
    STAGE32(Bsrc, ldb, 16384, 8192, 1, 1);
    asm volatile("s_waitcnt vmcnt(4)" ::: "memory");
  } else {
    asm volatile("s_waitcnt vmcnt(0)" ::: "memory");
  }
  FENCE; BARX; FENCE;

  int cur = 0, nxt = 16384, fut = 32768;       // u16-elem buffer offsets
  for (int t = 0; t < NT; ++t){
    DO_T(t, cur, fut)
    int tmp = cur; cur = nxt; nxt = fut; fut = tmp;
  }

  if (EPI == 0){
    float* C = (float*)Cp;
    #pragma unroll
    for (int mi = 0; mi < 8; mi++){
      int64_t gr = m0 + wr * 128 + mi * 16 + q4;
      #pragma unroll
      for (int ni = 0; ni < 4; ni++){
        int64_t gc = n0 + wc * 64 + ni * 16 + c16;
        v4f a = acc[mi][ni];
        float bo = auxf2[gc];
        #pragma unroll
        for (int r = 0; r < 4; r++)
          C[(gr + r) * ldc + gc] = a[r] + auxf1[(gr + r) * ldc + gc] + bo;
      }
    }
    return;
  }

  // bf16 epilogue: per-wave LDS transpose, packed 16B stores.
  u16* Cb = (u16*)Cp;
  float* scr = (float*)smd + wid * 528;
  const int erow = lane >> 2, eseg = lane & 3;
  #pragma unroll
  for (int mi = 0; mi < 8; mi++){
    #pragma unroll
    for (int nh = 0; nh < 2; nh++){
      #pragma unroll
      for (int ni = 0; ni < 2; ni++){
        v4f a = acc[mi][nh * 2 + ni];
        #pragma unroll
        for (int r = 0; r < 4; r++){
          float vv = a[r];
          if (EPI == 1) vv = geluf(vv);
          scr[(q4 + r) * 33 + ni * 16 + c16] = vv;
        }
      }
      float o[8];
      #pragma unroll
      for (int kq = 0; kq < 8; kq++) o[kq] = scr[erow * 33 + eseg * 8 + kq];
      int64_t gr = m0 + wr * 128 + mi * 16 + erow;
      int64_t gc = n0 + wc * 64 + nh * 32 + eseg * 8;
      if (EPI == 2){
        U4 pv = *(const U4*)(aux1 + gr * ldc + gc);
        const u16* pp = (const u16*)&pv;
        #pragma unroll
        for (int kq = 0; kq < 8; kq++) o[kq] *= bf2f(pp[kq]);
      }
      U4 outp; u16* op = (u16*)&outp;
      #pragma unroll
      for (int kq = 0; kq < 8; kq++) op[kq] = f2bf(o[kq]);
      *(U4*)(Cb + gr * ldc + gc) = outp;
    }
  }
}

// ======= FUSED t = gelu(xn @ Wv^T) * (y @ Wuc^T), 256x128 tile =======
// Both GEMMs share the output tile: rows = sequence (m), cols = gate dim (n).
// accV and accU are C-fragments of the SAME MFMA decomposition -> identical
// lane->(row,col) maps -> t is a register-level elementwise multiply. This
// deletes the 134MB v write + 134MB v read and one kernel's rounds.
// 512 thr = 8 waves (wr: 128-row half, wc: 32-col strip). BK=64 double-buffer,
// buffer = A[256][64] 32KB + B[128][64] 16KB = 48KB; LDS 96KB. Loop1 K=512
// (8 tiles), then loop2 staging issued BEFORE the in-register gelu (T14: HBM
// latency hides under ~1000 VALU), vmcnt(6) counted; loop2 K=128 (2 tiles).
#define STAGEF(SRC, LD, TBASE, SEL, KT)                                         \
  { const u16* _g = (SRC) + (int64_t)(KT) * 64 + (int64_t)((SEL) * 128 + wid * 8) * (LD); \
    u16* _lb = (TBASE) + ((SEL) * 128 + wid * 8) * 64;                          \
    ldsload16(_g, _lb);                                                         \
    ldsload16(_g + (int64_t)64 * (LD), _lb + 64 * 64);                          \
  }

// ds_read + 32 MFMA of one 48KB buffer into ACC (split mi halves: peak af=32B)
#define CFT(CURB, ACC)                                                          \
  {                                                                             \
    const char* Ac = (const char*)(CURB);                                       \
    const char* Bc = (const char*)(CURB) + 32768;                               \
    _Pragma("unroll")                                                           \
    for (int ni = 0; ni < 2; ni++){                                             \
      bfq[ni][0] = *(const short8*)(Bc + bbase + ni * 2048 + kx0);              \
      bfq[ni][1] = *(const short8*)(Bc + bbase + ni * 2048 + kx1);              \
    }                                                                           \
    _Pragma("unroll")                                                           \
    for (int mi = 0; mi < 4; mi++){                                             \
      af[mi][0] = *(const short8*)(Ac + abase + mi * 2048 + kx0);               \
      af[mi][1] = *(const short8*)(Ac + abase + mi * 2048 + kx1);               \
    }                                                                           \
    __builtin_amdgcn_s_setprio(1);                                              \
    _Pragma("unroll")                                                           \
    for (int mi = 0; mi < 4; mi++)                                              \
      _Pragma("unroll")                                                         \
      for (int ni = 0; ni < 2; ni++){                                           \
        ACC[mi][ni] = __builtin_amdgcn_mfma_f32_16x16x32_bf16(                  \
            af[mi][0], bfq[ni][0], ACC[mi][ni], 0, 0, 0);                       \
        ACC[mi][ni] = __builtin_amdgcn_mfma_f32_16x16x32_bf16(                  \
            af[mi][1], bfq[ni][1], ACC[mi][ni], 0, 0, 0);                       \
      }                                                                         \
    __builtin_amdgcn_s_setprio(0);                                              \
    _Pragma("unroll")                                                           \
    for (int mi = 0; mi < 4; mi++){                                             \
      af[mi][0] = *(const short8*)(Ac + 8192 + abase + mi * 2048 + kx0);        \
      af[mi][1] = *(const short8*)(Ac + 8192 + abase + mi * 2048 + kx1);        \
    }                                                                           \
    __builtin_amdgcn_s_setprio(1);                                              \
    _Pragma("unroll")                                                           \
    for (int mi = 0; mi < 4; mi++)                                              \
      _Pragma("unroll")                                                         \
      for (int ni = 0; ni < 2; ni++){                                           \
        ACC[4 + mi][ni] = __builtin_amdgcn_mfma_f32_16x16x32_bf16(              \
            af[mi][0], bfq[ni][0], ACC[4 + mi][ni], 0, 0, 0);                   \
        ACC[4 + mi][ni] = __builtin_amdgcn_mfma_f32_16x16x32_bf16(              \
            af[mi][1], bfq[ni][1], ACC[4 + mi][ni], 0, 0, 0);                   \
      }                                                                         \
    __builtin_amdgcn_s_setprio(0);                                              \
  }

#define DO_FT(T_, NT_, CURB, NXTB, ASRC, ALD, BSRC, BLD, ACC)                   \
  {                                                                             \
    if ((T_) + 1 < (NT_)){                                                      \
      STAGEF(ASRC, ALD, (NXTB),         0, (T_) + 1);                           \
      STAGEF(ASRC, ALD, (NXTB),         1, (T_) + 1);                           \
      STAGEF(BSRC, BLD, (NXTB) + 16384, 0, (T_) + 1);                           \
    }                                                                           \
    CFT(CURB, ACC)                                                              \
    asm volatile("s_waitcnt lgkmcnt(0)" ::: "memory");                          \
    if ((T_) + 1 < (NT_)) asm volatile("s_waitcnt vmcnt(0)" ::: "memory");      \
    FENCE; BARX; FENCE;                                                         \
  }

__global__ __launch_bounds__(512) void k_fused(
    const u16* __restrict__ xn,    // [32768,512]
    const u16* __restrict__ Wv,    // [2048,512]
    const u16* __restrict__ yb,    // [32768,128]
    const u16* __restrict__ Wuc,   // [2048,128]
    u16* __restrict__ T)           // [32768,2048]
{
  extern __shared__ __align__(16) u16 smd[];   // 2 x 48KB
  const int tid = threadIdx.x, wid = tid >> 6, lane = tid & 63;
  const int wr = wid >> 2, wc = wid & 3, c16 = lane & 15;
  const int q4 = (lane >> 4) << 2;

  int bx = blockIdx.x, by = blockIdx.y;        // bijective XCD swizzle
  if ((gridDim.y & 7) == 0 && gridDim.x > 1){
    u32 idx = by * gridDim.x + bx;
    u32 xcd = idx & 7, s = idx >> 3;
    bx = s % gridDim.x;
    by = (s / gridDim.x) * 8 + xcd;
  }
  const int64_t m0 = (int64_t)by * 256;
  const int64_t n0 = (int64_t)bx * 128;

  const int rowin = lane >> 3;
  const int colel = 8 * ((lane & 7) ^ rowin);
  const u16* Av = xn  + (m0 + rowin) * 512 + colel;
  const u16* Bv = Wv  + (n0 + rowin) * 512 + colel;
  const u16* Au = yb  + (m0 + rowin) * 128 + colel;
  const u16* Bu = Wuc + (n0 + rowin) * 128 + colel;

  const int kx0 = ((lane >> 4) << 4) ^ ((lane & 7) << 4);
  const int kx1 = kx0 ^ 64;
  const int abase = (wr * 128 + c16) * 128;    // A row bytes (mi=0)
  const int bbase = (wc * 32 + c16) * 128;     // B row bytes (ni=0)

  u16* buf0 = smd;                 // 24576 u16 = 48KB each
  u16* buf1 = smd + 24576;

  v4f accV[8][2], accU[8][2];
  #pragma unroll
  for (int i = 0; i < 8; i++)
    #pragma unroll
    for (int j = 0; j < 2; j++){ accV[i][j] = (v4f)0.0f; accU[i][j] = (v4f)0.0f; }

  short8 af[4][2], bfq[2][2];

  // ---- loop1: accV = xn @ Wv^T over K=512 (8 tiles, BK=64) ----
  STAGEF(Av, 512, buf0,         0, 0);
  STAGEF(Av, 512, buf0,         1, 0);
  STAGEF(Bv, 512, buf0 + 16384, 0, 0);
  asm volatile("s_waitcnt vmcnt(0)" ::: "memory");
  FENCE; BARX; FENCE;
  for (int t = 0; t < 8; t += 2){
    DO_FT(t,     8, buf0, buf1, Av, 512, Bv, 512, accV)
    DO_FT(t + 1, 8, buf1, buf0, Av, 512, Bv, 512, accV)
  }

  // ---- stage loop2 (both tiles), gelu accV under the load latency (T14) ----
  STAGEF(Au, 128, buf0,         0, 0);
  STAGEF(Au, 128, buf0,         1, 0);
  STAGEF(Bu, 128, buf0 + 16384, 0, 0);
  STAGEF(Au, 128, buf1,         0, 1);
  STAGEF(Au, 128, buf1,         1, 1);
  STAGEF(Bu, 128, buf1 + 16384, 0, 1);
  #pragma unroll
  for (int i = 0; i < 8; i++)
    #pragma unroll
    for (int j = 0; j < 2; j++)
      #pragma unroll
      for (int r = 0; r < 4; r++)
        accV[i][j][r] = geluf(accV[i][j][r]);
  asm volatile("s_waitcnt vmcnt(6)" ::: "memory");   // tile0 confirmed
  FENCE; BARX; FENCE;

  // ---- loop2: accU = y @ Wuc^T over K=128 (2 tiles) ----
  CFT(buf0, accU)
  asm volatile("s_waitcnt lgkmcnt(0)" ::: "memory");
  asm volatile("s_waitcnt vmcnt(0)" ::: "memory");   // tile1 confirmed
  FENCE; BARX; FENCE;
  CFT(buf1, accU)

  // ---- epilogue: t = accU * accV, bf16, per-wave LDS transpose ----
  float* scr = (float*)smd + wid * 528;              // 16x33 f32, wave-private
  const int erow = lane >> 2, eseg = lane & 3;
  #pragma unroll
  for (int mi = 0; mi < 8; mi++){
    #pragma unroll
    for (int ni = 0; ni < 2; ni++){
      v4f u = accU[mi][ni], g = accV[mi][ni];
      #pragma unroll
      for (int r = 0; r < 4; r++)
        scr[(q4 + r) * 33 + ni * 16 + c16] = u[r] * g[r];
    }
    float o[8];
    #pragma unroll
    for (int kq = 0; kq < 8; kq++) o[kq] = scr[erow * 33 + eseg * 8 + kq];
    int64_t gr = m0 + wr * 128 + mi * 16 + erow;
    int64_t gc = n0 + wc * 32 + eseg * 8;
    U4 outp; u16* op = (u16*)&outp;
    #pragma unroll
    for (int kq = 0; kq < 8; kq++) op[kq] = f2bf(o[kq]);
    *(U4*)(T + gr * 2048 + gc) = outp;
  }
}

extern "C" void kernel_launch(void* const* d_in, const int* in_sizes, int n_in,
                              void* d_out, int out_size, void* d_ws, size_t ws_size,
                              hipStream_t stream) {
  (void)in_sizes; (void)n_in; (void)out_size; (void)ws_size;
  const float* x      = (const float*)d_in[0];
  const float* norm_g = (const float*)d_in[1];
  const float* norm_b = (const float*)d_in[2];
  const float* W_v    = (const float*)d_in[3];
  const float* W_u    = (const float*)d_in[4];
  const float* W_uc   = (const float*)d_in[5];
  const float* W_o    = (const float*)d_in[6];
  const float* b_o    = (const float*)d_in[7];
  const float* dss_g  = (const float*)d_in[8];
  const float* dss_b  = (const float*)d_in[9];
  const float* lam_re = (const float*)d_in[10];
  const float* lam_im = (const float*)d_in[11];
  const float* C_re   = (const float*)d_in[12];
  const float* C_im   = (const float*)d_in[13];
  const float* D_skip = (const float*)d_in[14];

  // ---- d_out (67.1 MB f32) doubles as scratch for xn + 2 bf16 weights
  //      (xn and Wv_b now live until k_fused, still before the final GEMM) ----
  char* ob = (char*)d_out;
  u16* xn    = (u16*)(ob);                         // 33,554,432 B
  u16* Wv_b  = (u16*)(ob + 33554432ull);           //  2,097,152 B
  u16* Wu_b  = (u16*)(ob + 35651584ull);           //    131,072 B

  // ---- workspace layout (aliased by lifetime), total ~224 MiB ----
  char* ws = (char*)d_ws;
  const size_t R1      = 134217728ull;             // t buffer | (Rcat | WT)
  const size_t OFF_UN  = R1 + 33554432ull;
  const size_t OFF_UNT = OFF_UN + 8388608ull;      // unT, later y
  const size_t OFF_R2  = OFF_UNT + 8388608ull;     // S -> (Ycross | Yloc)
  const size_t OFF_TAB = OFF_R2 + 33554432ull;

  u16*  v     = (u16*)(ws + 0);                    // t [32768,2048] bf16
  u16*  u     = (u16*)(ws + R1);
  u16*  Rcat  = (u16*)(ws + R1);                   // 16.8 MB
  u16*  WT    = (u16*)(ws + R1 + 16777216ull);     // 16.8 MB
  u16*  un    = (u16*)(ws + OFF_UN);
  u16*  unT   = (u16*)(ws + OFF_UNT);
  u16*  y     = (u16*)(ws + OFF_UNT);
  float* S    = (float*)(ws + OFF_R2);
  float* Ycross = (float*)(ws + OFF_R2);
  float* Yloc = (float*)(ws + OFF_R2 + 16777216ull);
  char* tp = ws + OFF_TAB;
  u16*  ZC   = (u16*)tp;            tp += 1048576;
  u16*  PC   = (u16*)tp;            tp += 1048576;
  u16*  VC   = (u16*)tp;            tp += 1048576;
  u16*  ccat = (u16*)tp;            tp += 262144;
  float* cre = (float*)tp;          tp += 262144;
  float* cim = (float*)tp;          tp += 262144;
  float* zT  = (float*)tp;          tp += 4096;
  float* kern= (float*)tp;          tp += 262144;
  u16*  Wo_b = (u16*)tp;            tp += 2097152;
  u16*  Wuc_b= (u16*)tp;            tp += 524288;

  // weight conversions (f32 -> bf16), one launch
  k_cvt4<<<9472, 256, 0, stream>>>(W_v, Wv_b, 2048 * 512,
                                   W_u, Wu_b, 128 * 512,
                                   W_uc, Wuc_b, 2048 * 128,
                                   W_o, Wo_b, 512 * 2048);

  k_ln1<<<BL, 256, 0, stream>>>(x, norm_g, norm_b, xn);
  k_prep<<<512, 512, 0, stream>>>(lam_re, lam_im, C_re, C_im, ZC, PC, VC, ccat, cre, cim, zT);
  // kern while VC/ccat are L2-hot
  k_kern<<<512, 128, 0, stream>>>(VC, ccat, kern);

  // u = gelu(xn @ W_u^T)   [32768,128] bf16 (N=128 -> old template)
  k_gemm<1><<<dim3(1, 256, 1), 256, 0, stream>>>(xn, 512, 0, Wu_b, 512, 0, u, 128, 0, 512, 128, nullptr, nullptr, nullptr);
  k_ln2<<<BL / 4, 256, 0, stream>>>(u, dss_g, dss_b, un);
  k_transpose<<<512, 256, 0, stream>>>(un, unT);

  k_rcat<<<16384, 512, 0, stream>>>(kern, Rcat);

  // chunk states: S[m,n'] = sum_i unT[m,i]*ZC[n',i]  [8192,1024] f32
  k_gemm<0><<<dim3(8, 64, 1), 256, 0, stream>>>(unT, 512, 0, ZC, 512, 0, S, 1024, 0, 512, 1024, nullptr, nullptr, nullptr);
  k_scan<<<1024, 256, 0, stream>>>(S, cre, cim, zT, WT);
  // injection: Ycross[i,m] = sum_n' PC[i,n']*WT[m,n']  [512,8192] f32
  k_gemm<0><<<dim3(64, 4, 1), 256, 0, stream>>>(PC, 1024, 0, WT, 1024, 0, Ycross, 8192, 0, 1024, 8192, nullptr, nullptr, nullptr);
  // local conv via block-Toeplitz, single launch (TRI mode: by = i_blk)
  k_gemm<0, true><<<dim3(1, 4, 128), 256, 0, stream>>>(
      Rcat, 512, 65536, unT, 65536, 512, Yloc, 64, 32768, 512, 64, nullptr, nullptr, nullptr);
  // y assembled with coalesced Yloc reads (LDS transpose per ii)
  k_assemble2<<<512, 512, 0, stream>>>(Yloc, Ycross, un, D_skip, y);

  // t = gelu(xn @ W_v^T) * (y @ W_uc^T)   -- fused, no v round-trip
  k_fused<<<dim3(16, 128), 512, 98304, stream>>>(xn, Wv_b, y, Wuc_b, v);
  // out = t @ W_o^T + b_o + x   (f32 out)
  k_gemm256<0><<<dim3(2, 128), 512, 98304, stream>>>(v, 2048, Wo_b, 2048, d_out, 512, 2048, nullptr, x, b_o);
}